// Round 1
// 927.084 us; speedup vs baseline: 1.9979x; 1.9979x over previous
//
#include <hip/hip_runtime.h>
#include <hip/hip_bf16.h>
#include <math.h>

typedef __hip_bfloat16 bf16;
typedef __bf16 bf16x8 __attribute__((ext_vector_type(8)));
typedef float f32x4 __attribute__((ext_vector_type(4)));

typedef __attribute__((address_space(3))) void lds_void;
typedef const __attribute__((address_space(1))) void gbl_void;

__device__ __forceinline__ float b2f(bf16 v) { return __bfloat162float(v); }
__device__ __forceinline__ bf16 f2b(float v) { return __float2bfloat16(v); }

__device__ __forceinline__ f32x4 shfl_xor4(f32x4 v, int m) {
  f32x4 o;
  o[0] = __shfl_xor(v[0], m);
  o[1] = __shfl_xor(v[1], m);
  o[2] = __shfl_xor(v[2], m);
  o[3] = __shfl_xor(v[3], m);
  return o;
}
__device__ __forceinline__ f32x4 max4(f32x4 a, f32x4 b) {
  f32x4 o;
  o[0] = fmaxf(a[0], b[0]); o[1] = fmaxf(a[1], b[1]);
  o[2] = fmaxf(a[2], b[2]); o[3] = fmaxf(a[3], b[3]);
  return o;
}
__device__ __forceinline__ f32x4 exp4(f32x4 a) {
  f32x4 o;
  o[0] = __expf(a[0]); o[1] = __expf(a[1]);
  o[2] = __expf(a[2]); o[3] = __expf(a[3]);
  return o;
}

// ---------------------------------------------------------------------------
// dtype detection (inputs bf16 vs fp32), device-side, deterministic per call
// ---------------------------------------------------------------------------
__global__ void detect_dtype(const unsigned int* __restrict__ x, int* __restrict__ flag) {
  int cnt = 0;
  for (int i = 0; i < 128; ++i) {
    unsigned int lo = x[i] & 0xFFFFu;
    unsigned int e = (lo >> 7) & 0xFFu;
    if (e >= 100u && e <= 140u) ++cnt;
  }
  *flag = (cnt >= 96) ? 1 : 0;
}

__global__ void convert_in(const void* __restrict__ src, bf16* __restrict__ dst,
                           int n, const int* __restrict__ flag) {
  int i = blockIdx.x * 256 + threadIdx.x;
  if (i >= n) return;
  dst[i] = (*flag) ? ((const bf16*)src)[i] : f2b(((const float*)src)[i]);
}

__global__ void emit_kernel(const float* __restrict__ xf, const int* __restrict__ flag,
                            void* __restrict__ out) {
  int i = blockIdx.x * 256 + threadIdx.x;
  if (*flag) ((bf16*)out)[i] = f2b(xf[i]);
  else       ((float*)out)[i] = xf[i];
}

// ---------------------------------------------------------------------------
// Generic GEMM: C = alpha * A @ Bt^T (+bias +resid), bf16 in, fp32 acc.
// M, N multiples of 128; K multiple of 64 (no ragged handling).
// Staging: async global->LDS via global_load_lds width=16 (m97 structure).
// LDS layout is linear in lane order (wave-uniform dest + lane*16B), which
// matches the row-major [128][64] tile exactly.
// Epilogue: C tile staged through LDS (fp32) -> full-line vectorized stores.
// TAG only differentiates mangled names for per-dispatch rocprof attribution.
// ---------------------------------------------------------------------------
template<int TAG>
__global__ __launch_bounds__(256, 2) void gemm_bt(
    const bf16* __restrict__ A, int lda,
    const bf16* __restrict__ Bt, int ldb,
    float alpha,
    const float* __restrict__ resid,
    const bf16* __restrict__ bias,
    float* __restrict__ outf,
    bf16* __restrict__ outb,
    int ldc, int K)
{
  __shared__ char smem[32768] __attribute__((aligned(16)));
  __bf16* lA = (__bf16*)smem;
  __bf16* lB = (__bf16*)(smem + 16384);
  float*  lC = (float*)smem;           // epilogue alias (32 KB = 64x128 f32)

  int tid = threadIdx.x;
  int lane = tid & 63;
  int wave = tid >> 6;
  int quad = lane >> 4, l16 = lane & 15;
  int wm = (wave >> 1) * 64, wn = (wave & 1) * 64;
  int row0 = blockIdx.y * 128, col0 = blockIdx.x * 128;

  // per-lane source coordinates within a [128][64] bf16 tile, chunked 1KB/wave
  int rsub = lane >> 3, csub = (lane & 7) * 8;

  f32x4 acc[4][4];
#pragma unroll
  for (int a = 0; a < 4; ++a)
#pragma unroll
    for (int b = 0; b < 4; ++b) acc[a][b] = (f32x4){0.f, 0.f, 0.f, 0.f};

  for (int k0 = 0; k0 < K; k0 += 64) {
#pragma unroll
    for (int it = 0; it < 4; ++it) {
      int chunk = wave * 4 + it;           // 0..15, wave-uniform
      int r = chunk * 8 + rsub;            // row in tile
      __builtin_amdgcn_global_load_lds(
          (gbl_void*)(A + (long long)(row0 + r) * lda + (k0 + csub)),
          (lds_void*)(lA + chunk * 512), 16, 0, 0);
      __builtin_amdgcn_global_load_lds(
          (gbl_void*)(Bt + (long long)(col0 + r) * ldb + (k0 + csub)),
          (lds_void*)(lB + chunk * 512), 16, 0, 0);
    }
    __syncthreads();
#pragma unroll
    for (int ks = 0; ks < 2; ++ks) {
      int kb = ks * 32;
      bf16x8 af[4], bfr[4];
#pragma unroll
      for (int mi = 0; mi < 4; ++mi)
        af[mi] = *(const bf16x8*)&lA[(wm + mi * 16 + l16) * 64 + kb + quad * 8];
#pragma unroll
      for (int ni = 0; ni < 4; ++ni)
        bfr[ni] = *(const bf16x8*)&lB[(wn + ni * 16 + l16) * 64 + kb + quad * 8];
#pragma unroll
      for (int mi = 0; mi < 4; ++mi)
#pragma unroll
        for (int ni = 0; ni < 4; ++ni)
          acc[mi][ni] = __builtin_amdgcn_mfma_f32_16x16x32_bf16(
              af[mi], bfr[ni], acc[mi][ni], 0, 0, 0);
    }
    __syncthreads();
  }

  // --- LDS epilogue: two halves of 64 rows; full-line vectorized stores ---
#pragma unroll
  for (int half = 0; half < 2; ++half) {
    __syncthreads();
    if ((wave >> 1) == half) {
#pragma unroll
      for (int mi = 0; mi < 4; ++mi)
#pragma unroll
        for (int ni = 0; ni < 4; ++ni)
#pragma unroll
          for (int r = 0; r < 4; ++r)
            lC[(mi * 16 + quad * 4 + r) * 128 + wn + ni * 16 + l16] =
                acc[mi][ni][r] * alpha;
    }
    __syncthreads();
#pragma unroll
    for (int i = 0; i < 8; ++i) {
      int f = i * 256 + tid;             // 0..2047
      int row = f >> 5, cc = (f & 31) * 4;
      int m = row0 + half * 64 + row, n = col0 + cc;
      f32x4 v = *(const f32x4*)&lC[row * 128 + cc];
      long long ci = (long long)m * ldc + n;
      if (bias) {
        v[0] += b2f(bias[n]);     v[1] += b2f(bias[n + 1]);
        v[2] += b2f(bias[n + 2]); v[3] += b2f(bias[n + 3]);
      }
      if (resid) v += *(const f32x4*)&resid[ci];
      if (outf) *(f32x4*)&outf[ci] = v;
      if (outb) {
        bf16 c0 = f2b(v[0]), c1 = f2b(v[1]), c2 = f2b(v[2]), c3 = f2b(v[3]);
        ushort4 o = { *(unsigned short*)&c0, *(unsigned short*)&c1,
                      *(unsigned short*)&c2, *(unsigned short*)&c3 };
        *(ushort4*)&outb[ci] = o;
      }
    }
  }
}

// ---------------------------------------------------------------------------
// Split-K GEMM: pbuf[z][m][n] = A(K-chunk z) @ Bt^T. Plain dword stores.
// Same global_load_lds staging as gemm_bt.
// ---------------------------------------------------------------------------
__global__ __launch_bounds__(256, 2) void gemm_splitk(
    const bf16* __restrict__ A, int lda,
    const bf16* __restrict__ Bt, int ldb,
    float* __restrict__ pbuf, int ldc, int M, int KC)
{
  __shared__ __bf16 lA[128 * 64] __attribute__((aligned(16)));
  __shared__ __bf16 lB[128 * 64] __attribute__((aligned(16)));

  int koff = blockIdx.z * KC;
  float* outz = pbuf + (long long)blockIdx.z * M * ldc;
  int tid = threadIdx.x;
  int lane = tid & 63;
  int wave = tid >> 6;
  int quad = lane >> 4, l16 = lane & 15;
  int wm = (wave >> 1) * 64, wn = (wave & 1) * 64;
  int row0 = blockIdx.y * 128, col0 = blockIdx.x * 128;
  int rsub = lane >> 3, csub = (lane & 7) * 8;

  f32x4 acc[4][4];
#pragma unroll
  for (int a = 0; a < 4; ++a)
#pragma unroll
    for (int b = 0; b < 4; ++b) acc[a][b] = (f32x4){0.f, 0.f, 0.f, 0.f};

  for (int k0 = 0; k0 < KC; k0 += 64) {
#pragma unroll
    for (int it = 0; it < 4; ++it) {
      int chunk = wave * 4 + it;
      int r = chunk * 8 + rsub;
      __builtin_amdgcn_global_load_lds(
          (gbl_void*)(A + (long long)(row0 + r) * lda + (koff + k0 + csub)),
          (lds_void*)(lA + chunk * 512), 16, 0, 0);
      __builtin_amdgcn_global_load_lds(
          (gbl_void*)(Bt + (long long)(col0 + r) * ldb + (koff + k0 + csub)),
          (lds_void*)(lB + chunk * 512), 16, 0, 0);
    }
    __syncthreads();
#pragma unroll
    for (int ks = 0; ks < 2; ++ks) {
      int kb = ks * 32;
      bf16x8 af[4], bfr[4];
#pragma unroll
      for (int mi = 0; mi < 4; ++mi)
        af[mi] = *(const bf16x8*)&lA[(wm + mi * 16 + l16) * 64 + kb + quad * 8];
#pragma unroll
      for (int ni = 0; ni < 4; ++ni)
        bfr[ni] = *(const bf16x8*)&lB[(wn + ni * 16 + l16) * 64 + kb + quad * 8];
#pragma unroll
      for (int mi = 0; mi < 4; ++mi)
#pragma unroll
        for (int ni = 0; ni < 4; ++ni)
          acc[mi][ni] = __builtin_amdgcn_mfma_f32_16x16x32_bf16(
              af[mi], bfr[ni], acc[mi][ni], 0, 0, 0);
    }
    __syncthreads();
  }

#pragma unroll
  for (int mi = 0; mi < 4; ++mi)
#pragma unroll
    for (int ni = 0; ni < 4; ++ni) {
      int n = col0 + wn + ni * 16 + l16;
#pragma unroll
      for (int r = 0; r < 4; ++r) {
        int m = row0 + wm + mi * 16 + quad * 4 + r;
        outz[(long long)m * ldc + n] = acc[mi][ni][r];
      }
    }
}

// reduce 4 split-K partials + b2 + residual -> xf (fp32) and xbf (bf16)
__global__ void reduce_ff2(const float* __restrict__ pbuf, const bf16* __restrict__ bias,
                           float* __restrict__ xf, bf16* __restrict__ xbf) {
  int i = blockIdx.x * 256 + threadIdx.x;   // [0, 2048*1024)
  const int NT = 2048 * 1024;
  float v = xf[i] + b2f(bias[i & 1023]) +
            pbuf[i] + pbuf[i + NT] + pbuf[i + 2 * NT] + pbuf[i + 3 * NT];
  xf[i] = v;
  xbf[i] = f2b(v);
}

// ---------------------------------------------------------------------------
// Fused flash attention (unchanged)
// ---------------------------------------------------------------------------
template<int TK>
__device__ __forceinline__ void fa_tile(
    const bf16* __restrict__ kb, const bf16* __restrict__ vtb, int j0,
    const bf16x8 (&qa)[2][2], __bf16* lK, __bf16* lV, bf16* lPw,
    int tid, int quad, int l16,
    f32x4 (&accO)[2][4], f32x4 (&mrow)[2], f32x4 (&lrow)[2])
{
  constexpr int NT = TK / 16;
  constexpr int NCH = TK / 32;
  __syncthreads();
#pragma unroll
  for (int i = 0; i < TK / 32; ++i) {
    int t = i * 256 + tid;
    int r = t >> 3, c = (t & 7) * 8;
    *(uint4*)&lK[r * 72 + c] = *(const uint4*)&kb[(long long)(j0 + r) * 1024 + c];
  }
#pragma unroll
  for (int i = 0; i < TK / 32; ++i) {
    int t = i * 256 + tid;
    int d = t / (TK / 8), c = (t % (TK / 8)) * 8;
    *(uint4*)&lV[d * 136 + c] = *(const uint4*)&vtb[(long long)d * 8704 + j0 + c];
  }
  __syncthreads();

  f32x4 accS[2][NT];
#pragma unroll
  for (int mi = 0; mi < 2; ++mi)
#pragma unroll
    for (int ni = 0; ni < NT; ++ni) accS[mi][ni] = (f32x4){0.f, 0.f, 0.f, 0.f};

#pragma unroll
  for (int ni = 0; ni < NT; ++ni)
#pragma unroll
    for (int ks = 0; ks < 2; ++ks) {
      bf16x8 bfr = *(const bf16x8*)&lK[(ni * 16 + l16) * 72 + ks * 32 + quad * 8];
      accS[0][ni] = __builtin_amdgcn_mfma_f32_16x16x32_bf16(qa[0][ks], bfr, accS[0][ni], 0, 0, 0);
      accS[1][ni] = __builtin_amdgcn_mfma_f32_16x16x32_bf16(qa[1][ks], bfr, accS[1][ni], 0, 0, 0);
    }

#pragma unroll
  for (int mi = 0; mi < 2; ++mi) {
    f32x4 vmax = (f32x4){-INFINITY, -INFINITY, -INFINITY, -INFINITY};
#pragma unroll
    for (int ni = 0; ni < NT; ++ni) {
      accS[mi][ni] *= 0.125f;
      vmax = max4(vmax, accS[mi][ni]);
    }
#pragma unroll
    for (int m = 1; m <= 8; m <<= 1) vmax = max4(vmax, shfl_xor4(vmax, m));
    f32x4 mnew = max4(mrow[mi], vmax);
    f32x4 alpha = exp4(mrow[mi] - mnew);
    f32x4 rs = (f32x4){0.f, 0.f, 0.f, 0.f};
#pragma unroll
    for (int ni = 0; ni < NT; ++ni) {
      accS[mi][ni] = exp4(accS[mi][ni] - mnew);
      rs += accS[mi][ni];
    }
#pragma unroll
    for (int m = 1; m <= 8; m <<= 1) rs += shfl_xor4(rs, m);
    lrow[mi] = lrow[mi] * alpha + rs;
    mrow[mi] = mnew;
#pragma unroll
    for (int nd = 0; nd < 4; ++nd) accO[mi][nd] *= alpha;
  }

#pragma unroll
  for (int c = 0; c < NCH; ++c) {
#pragma unroll
    for (int mi = 0; mi < 2; ++mi)
#pragma unroll
      for (int u = 0; u < 2; ++u) {
#pragma unroll
        for (int r = 0; r < 4; ++r)
          lPw[(mi * 16 + quad * 4 + r) * 40 + u * 16 + l16] = f2b(accS[mi][c * 2 + u][r]);
      }
#pragma unroll
    for (int nd = 0; nd < 4; ++nd) {
      bf16x8 vb = *(const bf16x8*)&lV[(nd * 16 + l16) * 136 + c * 32 + quad * 8];
      bf16x8 pa0 = *(const bf16x8*)&lPw[(l16) * 40 + quad * 8];
      bf16x8 pa1 = *(const bf16x8*)&lPw[(16 + l16) * 40 + quad * 8];
      accO[0][nd] = __builtin_amdgcn_mfma_f32_16x16x32_bf16(pa0, vb, accO[0][nd], 0, 0, 0);
      accO[1][nd] = __builtin_amdgcn_mfma_f32_16x16x32_bf16(pa1, vb, accO[1][nd], 0, 0, 0);
    }
  }
}

__global__ __launch_bounds__(256, 1) void flash_attn(
    const bf16* __restrict__ q, const bf16* __restrict__ k,
    const bf16* __restrict__ vt, bf16* __restrict__ att)
{
  __shared__ __bf16 lK[128 * 72] __attribute__((aligned(16)));
  __shared__ __bf16 lV[64 * 136] __attribute__((aligned(16)));
  __shared__ __bf16 lP[4][32 * 40] __attribute__((aligned(16)));

  int idx = blockIdx.x;
  int b = idx >> 5, h = (idx >> 1) & 15, half = idx & 1;
  int tid = threadIdx.x, wave = tid >> 6, lane = tid & 63;
  int quad = lane >> 4, l16 = lane & 15;
  int qrow0 = b * 256 + half * 128 + wave * 32;

  const bf16* kb  = k  + (long long)b * 1088 * 1024 + h * 64;
  const bf16* vtb = vt + (long long)(h * 64) * 8704 + b * 1088;
  bf16* lPw = (bf16*)&lP[wave][0];

  bf16x8 qa[2][2];
#pragma unroll
  for (int mi = 0; mi < 2; ++mi)
#pragma unroll
    for (int ks = 0; ks < 2; ++ks)
      qa[mi][ks] = *(const bf16x8*)&q[(long long)(qrow0 + mi * 16 + l16) * 1024 +
                                      h * 64 + ks * 32 + quad * 8];

  f32x4 accO[2][4];
  f32x4 mrow[2], lrow[2];
#pragma unroll
  for (int mi = 0; mi < 2; ++mi) {
    mrow[mi] = (f32x4){-INFINITY, -INFINITY, -INFINITY, -INFINITY};
    lrow[mi] = (f32x4){0.f, 0.f, 0.f, 0.f};
#pragma unroll
    for (int nd = 0; nd < 4; ++nd) accO[mi][nd] = (f32x4){0.f, 0.f, 0.f, 0.f};
  }

  for (int jt = 0; jt < 8; ++jt)
    fa_tile<128>(kb, vtb, jt * 128, qa, lK, lV, lPw, tid, quad, l16, accO, mrow, lrow);
  fa_tile<64>(kb, vtb, 1024, qa, lK, lV, lPw, tid, quad, l16, accO, mrow, lrow);

#pragma unroll
  for (int mi = 0; mi < 2; ++mi) {
    f32x4 inv;
    inv[0] = 1.f / lrow[mi][0]; inv[1] = 1.f / lrow[mi][1];
    inv[2] = 1.f / lrow[mi][2]; inv[3] = 1.f / lrow[mi][3];
#pragma unroll
    for (int nd = 0; nd < 4; ++nd) {
      f32x4 o = accO[mi][nd] * inv;
#pragma unroll
      for (int r = 0; r < 4; ++r)
        att[(long long)(qrow0 + mi * 16 + quad * 4 + r) * 1024 +
            h * 64 + nd * 16 + l16] = f2b(o[r]);
    }
  }
}

// ---------------------------------------------------------------------------
// Elementwise / helper kernels
// ---------------------------------------------------------------------------
__global__ void init_x_kernel(const void* __restrict__ x, const int* __restrict__ flag,
                              float* __restrict__ xf, bf16* __restrict__ xbf) {
  int i = blockIdx.x * 256 + threadIdx.x;
  float v = (*flag) ? b2f(((const bf16*)x)[i]) : ((const float*)x)[i];
  xf[i] = v;
  xbf[i] = f2b(v);
}

__global__ void transpose_w(const void* __restrict__ in, bf16* __restrict__ out,
                            int R, int C, const int* __restrict__ flag) {
  __shared__ bf16 tile[32][33];
  long long zoff = (long long)blockIdx.z * R * C;
  const bf16* inb = (const bf16*)in + zoff;
  const float* inf = (const float*)in + zoff;
  out += zoff;
  int tx = threadIdx.x, ty = threadIdx.y;
  int c0 = blockIdx.x * 32, r0 = blockIdx.y * 32;
  int isb = *flag;
#pragma unroll
  for (int i = 0; i < 4; ++i) {
    long long off = (long long)(r0 + ty + i * 8) * C + (c0 + tx);
    tile[ty + i * 8][tx] = isb ? inb[off] : f2b(inf[off]);
  }
  __syncthreads();
#pragma unroll
  for (int i = 0; i < 4; ++i)
    out[(long long)(c0 + ty + i * 8) * R + (r0 + tx)] = tile[tx][ty + i * 8];
}

__global__ void rotary_q_kernel(bf16* __restrict__ q, const bf16* __restrict__ srcf) {
  int idx = blockIdx.x * 256 + threadIdx.x;
  int row = idx >> 9;
  int p = idx & 511;
  int h = p >> 5, i = p & 31;
  int d0 = h * 64 + 2 * i;
  int ntok = row & 255;
  float f = b2f(srcf[ntok * 64 + 2 * i]);
  float c = cosf(f), s = sinf(f);
  long long base = (long long)row * 1024 + d0;
  float q0 = b2f(q[base]), q1 = b2f(q[base + 1]);
  q[base]     = f2b(q0 * c - q1 * s);
  q[base + 1] = f2b(q1 * c + q0 * s);
}

__global__ void k_bias_rot_kernel(bf16* __restrict__ k, const bf16* __restrict__ tgtf,
                                  const bf16* __restrict__ rpe,
                                  const int* __restrict__ ridx, int layer) {
  int idx = blockIdx.x * 256 + threadIdx.x;
  int b = idx >> 19;
  int rem = idx & ((1 << 19) - 1);
  int j = rem >> 9;
  int p = rem & 511;
  int h = p >> 5, i = p & 31;
  int d0 = h * 64 + 2 * i;
  float bias = b2f(rpe[(layer * 405 + ridx[j >> 8]) * 16 + h]);
  float f = b2f(tgtf[j * 64 + 2 * i]);
  float c = cosf(f), s = sinf(f);
  long long base = (long long)(b * 1088 + j) * 1024 + d0;
  float k0 = b2f(k[base]) + bias, k1 = b2f(k[base + 1]) + bias;
  k[base]     = f2b(k0 * c - k1 * s);
  k[base + 1] = f2b(k1 * c + k0 * s);
}

__global__ void geglu_kernel(const bf16* __restrict__ hgl, bf16* __restrict__ y) {
  int idx = blockIdx.x * 256 + threadIdx.x;
  int m = idx >> 12, n = idx & 4095;
  float a = b2f(hgl[(long long)m * 8192 + n]);
  float g = b2f(hgl[(long long)m * 8192 + 4096 + n]);
  float ge = 0.5f * g * (1.0f + erff(g * 0.70710678118654752f));
  y[idx] = f2b(a * ge);
}

// ---------------------------------------------------------------------------
extern "C" void kernel_launch(void* const* d_in, const int* in_sizes, int n_in,
                              void* d_out, int out_size, void* d_ws, size_t ws_size,
                              hipStream_t stream) {
  (void)in_sizes; (void)n_in; (void)out_size; (void)ws_size;
  const void* x    = d_in[0];
  const void* cond = d_in[1];
  const void* Wq   = d_in[2];
  const void* Wk   = d_in[3];
  const void* Wv   = d_in[4];
  const void* Wo   = d_in[5];
  const void* bo   = d_in[6];
  const void* rpe  = d_in[7];
  const void* W1   = d_in[8];
  const void* b1   = d_in[9];
  const void* W2   = d_in[10];
  const void* b2   = d_in[11];
  const void* srcf = d_in[12];
  const void* tgtf = d_in[13];
  const int*  ridx = (const int*)d_in[14];

  char* w = (char*)d_ws;
  int* flag = (int*)w;   w += 256;
  bf16* WqT = (bf16*)w;  w += (size_t)2 * 1024 * 1024 * 2;
  bf16* WkT = (bf16*)w;  w += (size_t)2 * 1024 * 1024 * 2;
  bf16* WvT = (bf16*)w;  w += (size_t)2 * 1024 * 1024 * 2;
  bf16* WoT = (bf16*)w;  w += (size_t)2 * 1024 * 1024 * 2;
  bf16* W1T = (bf16*)w;  w += (size_t)2 * 8192 * 1024 * 2;
  bf16* W2T = (bf16*)w;  w += (size_t)2 * 4096 * 1024 * 2;
  bf16* condb = (bf16*)w; w += (size_t)8704 * 1024 * 2;
  bf16* bo_b = (bf16*)w;  w += 2048 * 2;
  bf16* rpe_b = (bf16*)w; w += 12960 * 2;
  bf16* b1_b = (bf16*)w;  w += 16384 * 2;
  bf16* b2_b = (bf16*)w;  w += 2048 * 2;
  bf16* srcf_b = (bf16*)w; w += 16384 * 2;
  bf16* tgtf_b = (bf16*)w; w += 65536 * 2;
  float* xf = (float*)w; w += (size_t)2048 * 1024 * 4;
  bf16* xbf = (bf16*)w;  w += (size_t)2048 * 1024 * 2;
  bf16* qbuf = (bf16*)w; w += (size_t)2048 * 1024 * 2;
  bf16* kbuf = (bf16*)w; w += (size_t)8704 * 1024 * 2;
  bf16* vTf = (bf16*)w;  w += (size_t)1024 * 8704 * 2;
  bf16* att = (bf16*)w;  w += (size_t)2048 * 1024 * 2;
  bf16* hgl = (bf16*)w;  w += (size_t)2048 * 8192 * 2;   // 32 MiB
  bf16* ybuf = (bf16*)w; w += (size_t)2048 * 4096 * 2;   // 16 MiB
  float* pbuf = (float*)hgl;  // split-K partials (4 x 8 MiB) alias dead hgl

  detect_dtype<<<1, 1, 0, stream>>>((const unsigned int*)x, flag);

  convert_in<<<34816, 256, 0, stream>>>(cond, condb, 8704 * 1024, flag);
  convert_in<<<8, 256, 0, stream>>>(bo, bo_b, 2048, flag);
  convert_in<<<51, 256, 0, stream>>>(rpe, rpe_b, 12960, flag);
  convert_in<<<64, 256, 0, stream>>>(b1, b1_b, 16384, flag);
  convert_in<<<8, 256, 0, stream>>>(b2, b2_b, 2048, flag);
  convert_in<<<64, 256, 0, stream>>>(srcf, srcf_b, 16384, flag);
  convert_in<<<256, 256, 0, stream>>>(tgtf, tgtf_b, 65536, flag);

  dim3 tb(32, 8);
  transpose_w<<<dim3(32, 32, 2),  tb, 0, stream>>>(Wq, WqT, 1024, 1024, flag);
  transpose_w<<<dim3(32, 32, 2),  tb, 0, stream>>>(Wk, WkT, 1024, 1024, flag);
  transpose_w<<<dim3(32, 32, 2),  tb, 0, stream>>>(Wv, WvT, 1024, 1024, flag);
  transpose_w<<<dim3(32, 32, 2),  tb, 0, stream>>>(Wo, WoT, 1024, 1024, flag);
  transpose_w<<<dim3(256, 32, 2), tb, 0, stream>>>(W1, W1T, 1024, 8192, flag);
  transpose_w<<<dim3(32, 128, 2), tb, 0, stream>>>(W2, W2T, 4096, 1024, flag);
  init_x_kernel<<<8192, 256, 0, stream>>>(x, flag, xf, xbf);

  for (int l = 0; l < 2; ++l) {
    const bf16* WqTl = WqT + (size_t)l * 1024 * 1024;
    const bf16* WkTl = WkT + (size_t)l * 1024 * 1024;
    const bf16* WvTl = WvT + (size_t)l * 1024 * 1024;
    const bf16* WoTl = WoT + (size_t)l * 1024 * 1024;
    const bf16* W1Tl = W1T + (size_t)l * 8192 * 1024;
    const bf16* W2Tl = W2T + (size_t)l * 4096 * 1024;

    // TAG 0: q = x @ Wq   (M=2048, N=1024)
    gemm_bt<0><<<dim3(8, 16), 256, 0, stream>>>(xbf, 1024, WqTl, 1024, 1.f,
        nullptr, nullptr, nullptr, qbuf, 1024, 1024);
    rotary_q_kernel<<<4096, 256, 0, stream>>>(qbuf, srcf_b);
    // TAG 1: V^T = Wv^T @ cond^T   (M=1024, N=8704)
    gemm_bt<1><<<dim3(68, 8), 256, 0, stream>>>(WvTl, 1024, condb, 1024, 1.f,
        nullptr, nullptr, nullptr, vTf, 8704, 1024);
    // TAG 2: k = cond @ Wk   (M=8704, N=1024)
    gemm_bt<2><<<dim3(8, 68), 256, 0, stream>>>(condb, 1024, WkTl, 1024, 1.f,
        nullptr, nullptr, nullptr, kbuf, 1024, 1024);
    k_bias_rot_kernel<<<16384, 256, 0, stream>>>(kbuf, tgtf_b, rpe_b, ridx, l);
    // fused attention
    flash_attn<<<256, 256, 0, stream>>>(qbuf, kbuf, vTf, att);
    // TAG 3: x = x + O @ Wo + bo   (M=2048, N=1024)
    gemm_bt<3><<<dim3(8, 16), 256, 0, stream>>>(att, 1024, WoTl, 1024, 1.f,
        xf, bo_b + (size_t)l * 1024, xf, xbf, 1024, 1024);
    // TAG 4: FF1 hgl = x @ W1 + b1   (M=2048, N=8192)
    gemm_bt<4><<<dim3(64, 16), 256, 0, stream>>>(xbf, 1024, W1Tl, 1024, 1.f,
        nullptr, b1_b + (size_t)l * 8192, nullptr, hgl, 8192, 1024);
    geglu_kernel<<<32768, 256, 0, stream>>>(hgl, ybuf);
    // FF2 split-K into partials (alias hgl, now dead) + fused reduce
    gemm_splitk<<<dim3(8, 16, 4), 256, 0, stream>>>(ybuf, 4096, W2Tl, 4096,
                                                    pbuf, 1024, 2048, 1024);
    reduce_ff2<<<8192, 256, 0, stream>>>(pbuf, b2_b + (size_t)l * 1024, xf, xbf);
  }

  emit_kernel<<<8192, 256, 0, stream>>>(xf, flag, d_out);
}

// Round 2
// 826.684 us; speedup vs baseline: 2.2405x; 1.1214x over previous
//
#include <hip/hip_runtime.h>
#include <hip/hip_bf16.h>
#include <math.h>

typedef __hip_bfloat16 bf16;
typedef __bf16 bf16x8 __attribute__((ext_vector_type(8)));
typedef float f32x4 __attribute__((ext_vector_type(4)));

typedef __attribute__((address_space(3))) void lds_void;
typedef const __attribute__((address_space(1))) void gbl_void;

__device__ __forceinline__ float b2f(bf16 v) { return __bfloat162float(v); }
__device__ __forceinline__ bf16 f2b(float v) { return __float2bfloat16(v); }

__device__ __forceinline__ f32x4 shfl_xor4(f32x4 v, int m) {
  f32x4 o;
  o[0] = __shfl_xor(v[0], m);
  o[1] = __shfl_xor(v[1], m);
  o[2] = __shfl_xor(v[2], m);
  o[3] = __shfl_xor(v[3], m);
  return o;
}
__device__ __forceinline__ f32x4 max4(f32x4 a, f32x4 b) {
  f32x4 o;
  o[0] = fmaxf(a[0], b[0]); o[1] = fmaxf(a[1], b[1]);
  o[2] = fmaxf(a[2], b[2]); o[3] = fmaxf(a[3], b[3]);
  return o;
}
__device__ __forceinline__ f32x4 exp4(f32x4 a) {
  f32x4 o;
  o[0] = __expf(a[0]); o[1] = __expf(a[1]);
  o[2] = __expf(a[2]); o[3] = __expf(a[3]);
  return o;
}

// ---------------------------------------------------------------------------
// dtype detection (inputs bf16 vs fp32), device-side, deterministic per call
// ---------------------------------------------------------------------------
__global__ void detect_dtype(const unsigned int* __restrict__ x, int* __restrict__ flag) {
  int cnt = 0;
  for (int i = 0; i < 128; ++i) {
    unsigned int lo = x[i] & 0xFFFFu;
    unsigned int e = (lo >> 7) & 0xFFu;
    if (e >= 100u && e <= 140u) ++cnt;
  }
  *flag = (cnt >= 96) ? 1 : 0;
}

__global__ void convert_in(const void* __restrict__ src, bf16* __restrict__ dst,
                           int n, const int* __restrict__ flag) {
  int i = blockIdx.x * 256 + threadIdx.x;
  if (i >= n) return;
  dst[i] = (*flag) ? ((const bf16*)src)[i] : f2b(((const float*)src)[i]);
}

__global__ void emit_kernel(const float* __restrict__ xf, const int* __restrict__ flag,
                            void* __restrict__ out) {
  int i = blockIdx.x * 256 + threadIdx.x;
  if (*flag) ((bf16*)out)[i] = f2b(xf[i]);
  else       ((float*)out)[i] = xf[i];
}

// ---------------------------------------------------------------------------
// 128^2-tile GEMM: C = alpha * A @ Bt^T (+bias +resid), bf16 in, fp32 acc.
// Double-buffered LDS, prefetch issued at tile start (global_load_lds w=16),
// ONE __syncthreads per K-tile. LDS XOR-swizzled (slot ^= row&7) to kill the
// 16-way ds_read_b128 bank conflict; swizzle applied as inverse on the global
// SOURCE address (linear LDS dest, rule: both-sides-or-neither).
// ---------------------------------------------------------------------------
template<int TAG>
__global__ __launch_bounds__(256, 2) void gemm_bt(
    const bf16* __restrict__ A, int lda,
    const bf16* __restrict__ Bt, int ldb,
    float alpha,
    const float* __restrict__ resid,
    const bf16* __restrict__ bias,
    float* __restrict__ outf,
    bf16* __restrict__ outb,
    int ldc, int K)
{
  __shared__ char smem[65536] __attribute__((aligned(16)));
  float* lC = (float*)smem;            // epilogue alias (32 KB = 64x128 f32)

  int tid = threadIdx.x;
  int lane = tid & 63;
  int wave = tid >> 6;
  int quad = lane >> 4, l16 = lane & 15;
  int wm = (wave >> 1) * 64, wn = (wave & 1) * 64;
  int row0 = blockIdx.y * 128, col0 = blockIdx.x * 128;

  // staging sources: 4 rounds x 256 threads x 16B per operand per K-tile.
  // LDS linear byte L = i*4096 + tid*16 -> logical row = L/128,
  // logical col-byte = (L%128) ^ ((row&7)<<4)  (involution).
  const bf16* asrc[4]; const bf16* bsrc[4];
#pragma unroll
  for (int i = 0; i < 4; ++i) {
    int row = i * 32 + (tid >> 3);
    int coff = ((tid & 7) * 16) ^ ((row & 7) << 4);   // bytes
    asrc[i] = A + (long long)(row0 + row) * lda + (coff >> 1);
    bsrc[i] = Bt + (long long)(col0 + row) * ldb + (coff >> 1);
  }
  int ldsbase = wave * 1024;  // + i*4096 (+buf, +16384 for B); lane*16 by HW

  f32x4 acc[4][4];
#pragma unroll
  for (int a = 0; a < 4; ++a)
#pragma unroll
    for (int b = 0; b < 4; ++b) acc[a][b] = (f32x4){0.f, 0.f, 0.f, 0.f};

  int nk = K >> 6;
  // prologue: stage tile 0 into buffer 0
#pragma unroll
  for (int i = 0; i < 4; ++i) {
    __builtin_amdgcn_global_load_lds((gbl_void*)(asrc[i]),
        (lds_void*)(smem + i * 4096 + ldsbase), 16, 0, 0);
    __builtin_amdgcn_global_load_lds((gbl_void*)(bsrc[i]),
        (lds_void*)(smem + 16384 + i * 4096 + ldsbase), 16, 0, 0);
  }
  __syncthreads();

  for (int t = 0; t < nk; ++t) {
    int buf = (t & 1) << 15;          // 0 / 32768
    int nbuf = buf ^ 32768;
    if (t + 1 < nk) {
      int k0 = (t + 1) << 6;
#pragma unroll
      for (int i = 0; i < 4; ++i) {
        __builtin_amdgcn_global_load_lds((gbl_void*)(asrc[i] + k0),
            (lds_void*)(smem + nbuf + i * 4096 + ldsbase), 16, 0, 0);
        __builtin_amdgcn_global_load_lds((gbl_void*)(bsrc[i] + k0),
            (lds_void*)(smem + nbuf + 16384 + i * 4096 + ldsbase), 16, 0, 0);
      }
    }
    const __bf16* lA = (const __bf16*)(smem + buf);
    const __bf16* lB = (const __bf16*)(smem + buf + 16384);
#pragma unroll
    for (int ks = 0; ks < 2; ++ks) {
      bf16x8 af[4], bfr[4];
#pragma unroll
      for (int mi = 0; mi < 4; ++mi) {
        int r = wm + mi * 16 + l16;
        af[mi] = *(const bf16x8*)&lA[r * 64 + ((ks * 32 + quad * 8) ^ ((r & 7) << 3))];
      }
#pragma unroll
      for (int ni = 0; ni < 4; ++ni) {
        int r = wn + ni * 16 + l16;
        bfr[ni] = *(const bf16x8*)&lB[r * 64 + ((ks * 32 + quad * 8) ^ ((r & 7) << 3))];
      }
      __builtin_amdgcn_s_setprio(1);
#pragma unroll
      for (int mi = 0; mi < 4; ++mi)
#pragma unroll
        for (int ni = 0; ni < 4; ++ni)
          acc[mi][ni] = __builtin_amdgcn_mfma_f32_16x16x32_bf16(
              af[mi], bfr[ni], acc[mi][ni], 0, 0, 0);
      __builtin_amdgcn_s_setprio(0);
    }
    __syncthreads();
  }

  // --- LDS epilogue: two halves of 64 rows; full-line vectorized stores ---
#pragma unroll
  for (int half = 0; half < 2; ++half) {
    __syncthreads();
    if ((wave >> 1) == half) {
#pragma unroll
      for (int mi = 0; mi < 4; ++mi)
#pragma unroll
        for (int ni = 0; ni < 4; ++ni)
#pragma unroll
          for (int r = 0; r < 4; ++r)
            lC[(mi * 16 + quad * 4 + r) * 128 + wn + ni * 16 + l16] =
                acc[mi][ni][r] * alpha;
    }
    __syncthreads();
#pragma unroll
    for (int i = 0; i < 8; ++i) {
      int f = i * 256 + tid;             // 0..2047
      int row = f >> 5, cc = (f & 31) * 4;
      int m = row0 + half * 64 + row, n = col0 + cc;
      f32x4 v = *(const f32x4*)&lC[row * 128 + cc];
      long long ci = (long long)m * ldc + n;
      if (bias) {
        v[0] += b2f(bias[n]);     v[1] += b2f(bias[n + 1]);
        v[2] += b2f(bias[n + 2]); v[3] += b2f(bias[n + 3]);
      }
      if (resid) v += *(const f32x4*)&resid[ci];
      if (outf) *(f32x4*)&outf[ci] = v;
      if (outb) {
        bf16 c0 = f2b(v[0]), c1 = f2b(v[1]), c2 = f2b(v[2]), c3 = f2b(v[3]);
        ushort4 o = { *(unsigned short*)&c0, *(unsigned short*)&c1,
                      *(unsigned short*)&c2, *(unsigned short*)&c3 };
        *(ushort4*)&outb[ci] = o;
      }
    }
  }
}

// ---------------------------------------------------------------------------
// 256^2-tile GEMM (8 waves, 128 KB LDS dbuf) for big-N shapes (FF1).
// Same prefetch/swizzle discipline as gemm_bt. bias + bf16-out epilogue.
// ---------------------------------------------------------------------------
__global__ __launch_bounds__(512, 2) void gemm256(
    const bf16* __restrict__ A, int lda,
    const bf16* __restrict__ Bt, int ldb,
    const bf16* __restrict__ bias,
    bf16* __restrict__ outb,
    int ldc, int K)
{
  __shared__ char smem[131072] __attribute__((aligned(16)));
  float* lC = (float*)smem;            // epilogue alias (128 KB = 128x256 f32)

  int tid = threadIdx.x;
  int lane = tid & 63;
  int wave = tid >> 6;
  int quad = lane >> 4, l16 = lane & 15;
  int wr = wave >> 2, wc = wave & 3;
  int wm = wr * 128, wn = wc * 64;
  int row0 = blockIdx.y * 256, col0 = blockIdx.x * 256;

  // staging: 4 rounds x 512 threads x 16B per operand per K-tile (32 KB each)
  const bf16* asrc[4]; const bf16* bsrc[4];
#pragma unroll
  for (int i = 0; i < 4; ++i) {
    int row = i * 64 + (tid >> 3);
    int coff = ((tid & 7) * 16) ^ ((row & 7) << 4);
    asrc[i] = A + (long long)(row0 + row) * lda + (coff >> 1);
    bsrc[i] = Bt + (long long)(col0 + row) * ldb + (coff >> 1);
  }
  int ldsbase = wave * 1024;   // + i*8192 (+buf, +32768 for B)

  f32x4 acc[8][4];
#pragma unroll
  for (int a = 0; a < 8; ++a)
#pragma unroll
    for (int b = 0; b < 4; ++b) acc[a][b] = (f32x4){0.f, 0.f, 0.f, 0.f};

  int nk = K >> 6;
#pragma unroll
  for (int i = 0; i < 4; ++i) {
    __builtin_amdgcn_global_load_lds((gbl_void*)(asrc[i]),
        (lds_void*)(smem + i * 8192 + ldsbase), 16, 0, 0);
    __builtin_amdgcn_global_load_lds((gbl_void*)(bsrc[i]),
        (lds_void*)(smem + 32768 + i * 8192 + ldsbase), 16, 0, 0);
  }
  __syncthreads();

  for (int t = 0; t < nk; ++t) {
    int buf = (t & 1) << 16;          // 0 / 65536
    int nbuf = buf ^ 65536;
    if (t + 1 < nk) {
      int k0 = (t + 1) << 6;
#pragma unroll
      for (int i = 0; i < 4; ++i) {
        __builtin_amdgcn_global_load_lds((gbl_void*)(asrc[i] + k0),
            (lds_void*)(smem + nbuf + i * 8192 + ldsbase), 16, 0, 0);
        __builtin_amdgcn_global_load_lds((gbl_void*)(bsrc[i] + k0),
            (lds_void*)(smem + nbuf + 32768 + i * 8192 + ldsbase), 16, 0, 0);
      }
    }
    const __bf16* lA = (const __bf16*)(smem + buf);
    const __bf16* lB = (const __bf16*)(smem + buf + 32768);
#pragma unroll
    for (int ks = 0; ks < 2; ++ks) {
      bf16x8 af[8], bfr[4];
#pragma unroll
      for (int mi = 0; mi < 8; ++mi) {
        int r = wm + mi * 16 + l16;
        af[mi] = *(const bf16x8*)&lA[r * 64 + ((ks * 32 + quad * 8) ^ ((r & 7) << 3))];
      }
#pragma unroll
      for (int ni = 0; ni < 4; ++ni) {
        int r = wn + ni * 16 + l16;
        bfr[ni] = *(const bf16x8*)&lB[r * 64 + ((ks * 32 + quad * 8) ^ ((r & 7) << 3))];
      }
      __builtin_amdgcn_s_setprio(1);
#pragma unroll
      for (int mi = 0; mi < 8; ++mi)
#pragma unroll
        for (int ni = 0; ni < 4; ++ni)
          acc[mi][ni] = __builtin_amdgcn_mfma_f32_16x16x32_bf16(
              af[mi], bfr[ni], acc[mi][ni], 0, 0, 0);
      __builtin_amdgcn_s_setprio(0);
    }
    __syncthreads();
  }

  // --- epilogue: 2 halves of 128 rows via fp32 LDS restage ---
#pragma unroll
  for (int h = 0; h < 2; ++h) {
    __syncthreads();
    if (wr == h) {
#pragma unroll
      for (int mi = 0; mi < 8; ++mi)
#pragma unroll
        for (int ni = 0; ni < 4; ++ni)
#pragma unroll
          for (int r = 0; r < 4; ++r)
            lC[(mi * 16 + quad * 4 + r) * 256 + wn + ni * 16 + l16] =
                acc[mi][ni][r];
    }
    __syncthreads();
#pragma unroll
    for (int it = 0; it < 16; ++it) {
      int f = it * 512 + tid;            // 0..8191
      int row = f >> 6, cc = (f & 63) * 4;
      int m = row0 + h * 128 + row, n = col0 + cc;
      f32x4 v = *(const f32x4*)&lC[row * 256 + cc];
      v[0] += b2f(bias[n]);     v[1] += b2f(bias[n + 1]);
      v[2] += b2f(bias[n + 2]); v[3] += b2f(bias[n + 3]);
      bf16 c0 = f2b(v[0]), c1 = f2b(v[1]), c2 = f2b(v[2]), c3 = f2b(v[3]);
      ushort4 o = { *(unsigned short*)&c0, *(unsigned short*)&c1,
                    *(unsigned short*)&c2, *(unsigned short*)&c3 };
      *(ushort4*)&outb[(long long)m * ldc + n] = o;
    }
  }
}

// ---------------------------------------------------------------------------
// Split-K GEMM: pbuf[z][m][n] = A(K-chunk z) @ Bt^T. Same dbuf+swizzle.
// ---------------------------------------------------------------------------
__global__ __launch_bounds__(256, 2) void gemm_splitk(
    const bf16* __restrict__ A, int lda,
    const bf16* __restrict__ Bt, int ldb,
    float* __restrict__ pbuf, int ldc, int M, int KC)
{
  __shared__ char smem[65536] __attribute__((aligned(16)));

  int koff = blockIdx.z * KC;
  float* outz = pbuf + (long long)blockIdx.z * M * ldc;
  int tid = threadIdx.x;
  int lane = tid & 63;
  int wave = tid >> 6;
  int quad = lane >> 4, l16 = lane & 15;
  int wm = (wave >> 1) * 64, wn = (wave & 1) * 64;
  int row0 = blockIdx.y * 128, col0 = blockIdx.x * 128;

  const bf16* asrc[4]; const bf16* bsrc[4];
#pragma unroll
  for (int i = 0; i < 4; ++i) {
    int row = i * 32 + (tid >> 3);
    int coff = ((tid & 7) * 16) ^ ((row & 7) << 4);
    asrc[i] = A + (long long)(row0 + row) * lda + koff + (coff >> 1);
    bsrc[i] = Bt + (long long)(col0 + row) * ldb + koff + (coff >> 1);
  }
  int ldsbase = wave * 1024;

  f32x4 acc[4][4];
#pragma unroll
  for (int a = 0; a < 4; ++a)
#pragma unroll
    for (int b = 0; b < 4; ++b) acc[a][b] = (f32x4){0.f, 0.f, 0.f, 0.f};

  int nk = KC >> 6;
#pragma unroll
  for (int i = 0; i < 4; ++i) {
    __builtin_amdgcn_global_load_lds((gbl_void*)(asrc[i]),
        (lds_void*)(smem + i * 4096 + ldsbase), 16, 0, 0);
    __builtin_amdgcn_global_load_lds((gbl_void*)(bsrc[i]),
        (lds_void*)(smem + 16384 + i * 4096 + ldsbase), 16, 0, 0);
  }
  __syncthreads();

  for (int t = 0; t < nk; ++t) {
    int buf = (t & 1) << 15;
    int nbuf = buf ^ 32768;
    if (t + 1 < nk) {
      int k0 = (t + 1) << 6;
#pragma unroll
      for (int i = 0; i < 4; ++i) {
        __builtin_amdgcn_global_load_lds((gbl_void*)(asrc[i] + k0),
            (lds_void*)(smem + nbuf + i * 4096 + ldsbase), 16, 0, 0);
        __builtin_amdgcn_global_load_lds((gbl_void*)(bsrc[i] + k0),
            (lds_void*)(smem + nbuf + 16384 + i * 4096 + ldsbase), 16, 0, 0);
      }
    }
    const __bf16* lA = (const __bf16*)(smem + buf);
    const __bf16* lB = (const __bf16*)(smem + buf + 16384);
#pragma unroll
    for (int ks = 0; ks < 2; ++ks) {
      bf16x8 af[4], bfr[4];
#pragma unroll
      for (int mi = 0; mi < 4; ++mi) {
        int r = wm + mi * 16 + l16;
        af[mi] = *(const bf16x8*)&lA[r * 64 + ((ks * 32 + quad * 8) ^ ((r & 7) << 3))];
      }
#pragma unroll
      for (int ni = 0; ni < 4; ++ni) {
        int r = wn + ni * 16 + l16;
        bfr[ni] = *(const bf16x8*)&lB[r * 64 + ((ks * 32 + quad * 8) ^ ((r & 7) << 3))];
      }
      __builtin_amdgcn_s_setprio(1);
#pragma unroll
      for (int mi = 0; mi < 4; ++mi)
#pragma unroll
        for (int ni = 0; ni < 4; ++ni)
          acc[mi][ni] = __builtin_amdgcn_mfma_f32_16x16x32_bf16(
              af[mi], bfr[ni], acc[mi][ni], 0, 0, 0);
      __builtin_amdgcn_s_setprio(0);
    }
    __syncthreads();
  }

#pragma unroll
  for (int mi = 0; mi < 4; ++mi)
#pragma unroll
    for (int ni = 0; ni < 4; ++ni) {
      int n = col0 + wn + ni * 16 + l16;
#pragma unroll
      for (int r = 0; r < 4; ++r) {
        int m = row0 + wm + mi * 16 + quad * 4 + r;
        outz[(long long)m * ldc + n] = acc[mi][ni][r];
      }
    }
}

// reduce 4 split-K partials + b2 + residual -> xf (fp32) and xbf (bf16)
__global__ void reduce_ff2(const float* __restrict__ pbuf, const bf16* __restrict__ bias,
                           float* __restrict__ xf, bf16* __restrict__ xbf) {
  int i = blockIdx.x * 256 + threadIdx.x;   // [0, 2048*1024)
  const int NT = 2048 * 1024;
  float v = xf[i] + b2f(bias[i & 1023]) +
            pbuf[i] + pbuf[i + NT] + pbuf[i + 2 * NT] + pbuf[i + 3 * NT];
  xf[i] = v;
  xbf[i] = f2b(v);
}

// ---------------------------------------------------------------------------
// Fused flash attention (unchanged)
// ---------------------------------------------------------------------------
template<int TK>
__device__ __forceinline__ void fa_tile(
    const bf16* __restrict__ kb, const bf16* __restrict__ vtb, int j0,
    const bf16x8 (&qa)[2][2], __bf16* lK, __bf16* lV, bf16* lPw,
    int tid, int quad, int l16,
    f32x4 (&accO)[2][4], f32x4 (&mrow)[2], f32x4 (&lrow)[2])
{
  constexpr int NT = TK / 16;
  constexpr int NCH = TK / 32;
  __syncthreads();
#pragma unroll
  for (int i = 0; i < TK / 32; ++i) {
    int t = i * 256 + tid;
    int r = t >> 3, c = (t & 7) * 8;
    *(uint4*)&lK[r * 72 + c] = *(const uint4*)&kb[(long long)(j0 + r) * 1024 + c];
  }
#pragma unroll
  for (int i = 0; i < TK / 32; ++i) {
    int t = i * 256 + tid;
    int d = t / (TK / 8), c = (t % (TK / 8)) * 8;
    *(uint4*)&lV[d * 136 + c] = *(const uint4*)&vtb[(long long)d * 8704 + j0 + c];
  }
  __syncthreads();

  f32x4 accS[2][NT];
#pragma unroll
  for (int mi = 0; mi < 2; ++mi)
#pragma unroll
    for (int ni = 0; ni < NT; ++ni) accS[mi][ni] = (f32x4){0.f, 0.f, 0.f, 0.f};

#pragma unroll
  for (int ni = 0; ni < NT; ++ni)
#pragma unroll
    for (int ks = 0; ks < 2; ++ks) {
      bf16x8 bfr = *(const bf16x8*)&lK[(ni * 16 + l16) * 72 + ks * 32 + quad * 8];
      accS[0][ni] = __builtin_amdgcn_mfma_f32_16x16x32_bf16(qa[0][ks], bfr, accS[0][ni], 0, 0, 0);
      accS[1][ni] = __builtin_amdgcn_mfma_f32_16x16x32_bf16(qa[1][ks], bfr, accS[1][ni], 0, 0, 0);
    }

#pragma unroll
  for (int mi = 0; mi < 2; ++mi) {
    f32x4 vmax = (f32x4){-INFINITY, -INFINITY, -INFINITY, -INFINITY};
#pragma unroll
    for (int ni = 0; ni < NT; ++ni) {
      accS[mi][ni] *= 0.125f;
      vmax = max4(vmax, accS[mi][ni]);
    }
#pragma unroll
    for (int m = 1; m <= 8; m <<= 1) vmax = max4(vmax, shfl_xor4(vmax, m));
    f32x4 mnew = max4(mrow[mi], vmax);
    f32x4 alpha = exp4(mrow[mi] - mnew);
    f32x4 rs = (f32x4){0.f, 0.f, 0.f, 0.f};
#pragma unroll
    for (int ni = 0; ni < NT; ++ni) {
      accS[mi][ni] = exp4(accS[mi][ni] - mnew);
      rs += accS[mi][ni];
    }
#pragma unroll
    for (int m = 1; m <= 8; m <<= 1) rs += shfl_xor4(rs, m);
    lrow[mi] = lrow[mi] * alpha + rs;
    mrow[mi] = mnew;
#pragma unroll
    for (int nd = 0; nd < 4; ++nd) accO[mi][nd] *= alpha;
  }

#pragma unroll
  for (int c = 0; c < NCH; ++c) {
#pragma unroll
    for (int mi = 0; mi < 2; ++mi)
#pragma unroll
      for (int u = 0; u < 2; ++u) {
#pragma unroll
        for (int r = 0; r < 4; ++r)
          lPw[(mi * 16 + quad * 4 + r) * 40 + u * 16 + l16] = f2b(accS[mi][c * 2 + u][r]);
      }
#pragma unroll
    for (int nd = 0; nd < 4; ++nd) {
      bf16x8 vb = *(const bf16x8*)&lV[(nd * 16 + l16) * 136 + c * 32 + quad * 8];
      bf16x8 pa0 = *(const bf16x8*)&lPw[(l16) * 40 + quad * 8];
      bf16x8 pa1 = *(const bf16x8*)&lPw[(16 + l16) * 40 + quad * 8];
      accO[0][nd] = __builtin_amdgcn_mfma_f32_16x16x32_bf16(pa0, vb, accO[0][nd], 0, 0, 0);
      accO[1][nd] = __builtin_amdgcn_mfma_f32_16x16x32_bf16(pa1, vb, accO[1][nd], 0, 0, 0);
    }
  }
}

__global__ __launch_bounds__(256, 1) void flash_attn(
    const bf16* __restrict__ q, const bf16* __restrict__ k,
    const bf16* __restrict__ vt, bf16* __restrict__ att)
{
  __shared__ __bf16 lK[128 * 72] __attribute__((aligned(16)));
  __shared__ __bf16 lV[64 * 136] __attribute__((aligned(16)));
  __shared__ __bf16 lP[4][32 * 40] __attribute__((aligned(16)));

  int idx = blockIdx.x;
  int b = idx >> 5, h = (idx >> 1) & 15, half = idx & 1;
  int tid = threadIdx.x, wave = tid >> 6, lane = tid & 63;
  int quad = lane >> 4, l16 = lane & 15;
  int qrow0 = b * 256 + half * 128 + wave * 32;

  const bf16* kb  = k  + (long long)b * 1088 * 1024 + h * 64;
  const bf16* vtb = vt + (long long)(h * 64) * 8704 + b * 1088;
  bf16* lPw = (bf16*)&lP[wave][0];

  bf16x8 qa[2][2];
#pragma unroll
  for (int mi = 0; mi < 2; ++mi)
#pragma unroll
    for (int ks = 0; ks < 2; ++ks)
      qa[mi][ks] = *(const bf16x8*)&q[(long long)(qrow0 + mi * 16 + l16) * 1024 +
                                      h * 64 + ks * 32 + quad * 8];

  f32x4 accO[2][4];
  f32x4 mrow[2], lrow[2];
#pragma unroll
  for (int mi = 0; mi < 2; ++mi) {
    mrow[mi] = (f32x4){-INFINITY, -INFINITY, -INFINITY, -INFINITY};
    lrow[mi] = (f32x4){0.f, 0.f, 0.f, 0.f};
#pragma unroll
    for (int nd = 0; nd < 4; ++nd) accO[mi][nd] = (f32x4){0.f, 0.f, 0.f, 0.f};
  }

  for (int jt = 0; jt < 8; ++jt)
    fa_tile<128>(kb, vtb, jt * 128, qa, lK, lV, lPw, tid, quad, l16, accO, mrow, lrow);
  fa_tile<64>(kb, vtb, 1024, qa, lK, lV, lPw, tid, quad, l16, accO, mrow, lrow);

#pragma unroll
  for (int mi = 0; mi < 2; ++mi) {
    f32x4 inv;
    inv[0] = 1.f / lrow[mi][0]; inv[1] = 1.f / lrow[mi][1];
    inv[2] = 1.f / lrow[mi][2]; inv[3] = 1.f / lrow[mi][3];
#pragma unroll
    for (int nd = 0; nd < 4; ++nd) {
      f32x4 o = accO[mi][nd] * inv;
#pragma unroll
      for (int r = 0; r < 4; ++r)
        att[(long long)(qrow0 + mi * 16 + quad * 4 + r) * 1024 +
            h * 64 + nd * 16 + l16] = f2b(o[r]);
    }
  }
}

// ---------------------------------------------------------------------------
// Elementwise / helper kernels
// ---------------------------------------------------------------------------
__global__ void init_x_kernel(const void* __restrict__ x, const int* __restrict__ flag,
                              float* __restrict__ xf, bf16* __restrict__ xbf) {
  int i = blockIdx.x * 256 + threadIdx.x;
  float v = (*flag) ? b2f(((const bf16*)x)[i]) : ((const float*)x)[i];
  xf[i] = v;
  xbf[i] = f2b(v);
}

__global__ void transpose_w(const void* __restrict__ in, bf16* __restrict__ out,
                            int R, int C, const int* __restrict__ flag) {
  __shared__ bf16 tile[32][33];
  long long zoff = (long long)blockIdx.z * R * C;
  const bf16* inb = (const bf16*)in + zoff;
  const float* inf = (const float*)in + zoff;
  out += zoff;
  int tx = threadIdx.x, ty = threadIdx.y;
  int c0 = blockIdx.x * 32, r0 = blockIdx.y * 32;
  int isb = *flag;
#pragma unroll
  for (int i = 0; i < 4; ++i) {
    long long off = (long long)(r0 + ty + i * 8) * C + (c0 + tx);
    tile[ty + i * 8][tx] = isb ? inb[off] : f2b(inf[off]);
  }
  __syncthreads();
#pragma unroll
  for (int i = 0; i < 4; ++i)
    out[(long long)(c0 + ty + i * 8) * R + (r0 + tx)] = tile[tx][ty + i * 8];
}

__global__ void rotary_q_kernel(bf16* __restrict__ q, const bf16* __restrict__ srcf) {
  int idx = blockIdx.x * 256 + threadIdx.x;
  int row = idx >> 9;
  int p = idx & 511;
  int h = p >> 5, i = p & 31;
  int d0 = h * 64 + 2 * i;
  int ntok = row & 255;
  float f = b2f(srcf[ntok * 64 + 2 * i]);
  float c = cosf(f), s = sinf(f);
  long long base = (long long)row * 1024 + d0;
  float q0 = b2f(q[base]), q1 = b2f(q[base + 1]);
  q[base]     = f2b(q0 * c - q1 * s);
  q[base + 1] = f2b(q1 * c + q0 * s);
}

__global__ void k_bias_rot_kernel(bf16* __restrict__ k, const bf16* __restrict__ tgtf,
                                  const bf16* __restrict__ rpe,
                                  const int* __restrict__ ridx, int layer) {
  int idx = blockIdx.x * 256 + threadIdx.x;
  int b = idx >> 19;
  int rem = idx & ((1 << 19) - 1);
  int j = rem >> 9;
  int p = rem & 511;
  int h = p >> 5, i = p & 31;
  int d0 = h * 64 + 2 * i;
  float bias = b2f(rpe[(layer * 405 + ridx[j >> 8]) * 16 + h]);
  float f = b2f(tgtf[j * 64 + 2 * i]);
  float c = cosf(f), s = sinf(f);
  long long base = (long long)(b * 1088 + j) * 1024 + d0;
  float k0 = b2f(k[base]) + bias, k1 = b2f(k[base + 1]) + bias;
  k[base]     = f2b(k0 * c - k1 * s);
  k[base + 1] = f2b(k1 * c + k0 * s);
}

__global__ void geglu_kernel(const bf16* __restrict__ hgl, bf16* __restrict__ y) {
  int idx = blockIdx.x * 256 + threadIdx.x;
  int m = idx >> 12, n = idx & 4095;
  float a = b2f(hgl[(long long)m * 8192 + n]);
  float g = b2f(hgl[(long long)m * 8192 + 4096 + n]);
  float ge = 0.5f * g * (1.0f + erff(g * 0.70710678118654752f));
  y[idx] = f2b(a * ge);
}

// ---------------------------------------------------------------------------
extern "C" void kernel_launch(void* const* d_in, const int* in_sizes, int n_in,
                              void* d_out, int out_size, void* d_ws, size_t ws_size,
                              hipStream_t stream) {
  (void)in_sizes; (void)n_in; (void)out_size; (void)ws_size;
  const void* x    = d_in[0];
  const void* cond = d_in[1];
  const void* Wq   = d_in[2];
  const void* Wk   = d_in[3];
  const void* Wv   = d_in[4];
  const void* Wo   = d_in[5];
  const void* bo   = d_in[6];
  const void* rpe  = d_in[7];
  const void* W1   = d_in[8];
  const void* b1   = d_in[9];
  const void* W2   = d_in[10];
  const void* b2   = d_in[11];
  const void* srcf = d_in[12];
  const void* tgtf = d_in[13];
  const int*  ridx = (const int*)d_in[14];

  char* w = (char*)d_ws;
  int* flag = (int*)w;   w += 256;
  bf16* WqT = (bf16*)w;  w += (size_t)2 * 1024 * 1024 * 2;
  bf16* WkT = (bf16*)w;  w += (size_t)2 * 1024 * 1024 * 2;
  bf16* WvT = (bf16*)w;  w += (size_t)2 * 1024 * 1024 * 2;
  bf16* WoT = (bf16*)w;  w += (size_t)2 * 1024 * 1024 * 2;
  bf16* W1T = (bf16*)w;  w += (size_t)2 * 8192 * 1024 * 2;
  bf16* W2T = (bf16*)w;  w += (size_t)2 * 4096 * 1024 * 2;
  bf16* condb = (bf16*)w; w += (size_t)8704 * 1024 * 2;
  bf16* bo_b = (bf16*)w;  w += 2048 * 2;
  bf16* rpe_b = (bf16*)w; w += 12960 * 2;
  bf16* b1_b = (bf16*)w;  w += 16384 * 2;
  bf16* b2_b = (bf16*)w;  w += 2048 * 2;
  bf16* srcf_b = (bf16*)w; w += 16384 * 2;
  bf16* tgtf_b = (bf16*)w; w += 65536 * 2;
  float* xf = (float*)w; w += (size_t)2048 * 1024 * 4;
  bf16* xbf = (bf16*)w;  w += (size_t)2048 * 1024 * 2;
  bf16* qbuf = (bf16*)w; w += (size_t)2048 * 1024 * 2;
  bf16* kbuf = (bf16*)w; w += (size_t)8704 * 1024 * 2;
  bf16* vTf = (bf16*)w;  w += (size_t)1024 * 8704 * 2;
  bf16* att = (bf16*)w;  w += (size_t)2048 * 1024 * 2;
  bf16* hgl = (bf16*)w;  w += (size_t)2048 * 8192 * 2;   // 32 MiB
  bf16* ybuf = (bf16*)w; w += (size_t)2048 * 4096 * 2;   // 16 MiB
  float* pbuf = (float*)hgl;  // split-K partials (4 x 8 MiB) alias dead hgl

  detect_dtype<<<1, 1, 0, stream>>>((const unsigned int*)x, flag);

  convert_in<<<34816, 256, 0, stream>>>(cond, condb, 8704 * 1024, flag);
  convert_in<<<8, 256, 0, stream>>>(bo, bo_b, 2048, flag);
  convert_in<<<51, 256, 0, stream>>>(rpe, rpe_b, 12960, flag);
  convert_in<<<64, 256, 0, stream>>>(b1, b1_b, 16384, flag);
  convert_in<<<8, 256, 0, stream>>>(b2, b2_b, 2048, flag);
  convert_in<<<64, 256, 0, stream>>>(srcf, srcf_b, 16384, flag);
  convert_in<<<256, 256, 0, stream>>>(tgtf, tgtf_b, 65536, flag);

  dim3 tb(32, 8);
  transpose_w<<<dim3(32, 32, 2),  tb, 0, stream>>>(Wq, WqT, 1024, 1024, flag);
  transpose_w<<<dim3(32, 32, 2),  tb, 0, stream>>>(Wk, WkT, 1024, 1024, flag);
  transpose_w<<<dim3(32, 32, 2),  tb, 0, stream>>>(Wv, WvT, 1024, 1024, flag);
  transpose_w<<<dim3(32, 32, 2),  tb, 0, stream>>>(Wo, WoT, 1024, 1024, flag);
  transpose_w<<<dim3(256, 32, 2), tb, 0, stream>>>(W1, W1T, 1024, 8192, flag);
  transpose_w<<<dim3(32, 128, 2), tb, 0, stream>>>(W2, W2T, 4096, 1024, flag);
  init_x_kernel<<<8192, 256, 0, stream>>>(x, flag, xf, xbf);

  for (int l = 0; l < 2; ++l) {
    const bf16* WqTl = WqT + (size_t)l * 1024 * 1024;
    const bf16* WkTl = WkT + (size_t)l * 1024 * 1024;
    const bf16* WvTl = WvT + (size_t)l * 1024 * 1024;
    const bf16* WoTl = WoT + (size_t)l * 1024 * 1024;
    const bf16* W1Tl = W1T + (size_t)l * 8192 * 1024;
    const bf16* W2Tl = W2T + (size_t)l * 4096 * 1024;

    // TAG 0: q = x @ Wq   (M=2048, N=1024)
    gemm_bt<0><<<dim3(8, 16), 256, 0, stream>>>(xbf, 1024, WqTl, 1024, 1.f,
        nullptr, nullptr, nullptr, qbuf, 1024, 1024);
    rotary_q_kernel<<<4096, 256, 0, stream>>>(qbuf, srcf_b);
    // TAG 1: V^T = Wv^T @ cond^T   (M=1024, N=8704)
    gemm_bt<1><<<dim3(68, 8), 256, 0, stream>>>(WvTl, 1024, condb, 1024, 1.f,
        nullptr, nullptr, nullptr, vTf, 8704, 1024);
    // TAG 2: k = cond @ Wk   (M=8704, N=1024)
    gemm_bt<2><<<dim3(8, 68), 256, 0, stream>>>(condb, 1024, WkTl, 1024, 1.f,
        nullptr, nullptr, nullptr, kbuf, 1024, 1024);
    k_bias_rot_kernel<<<16384, 256, 0, stream>>>(kbuf, tgtf_b, rpe_b, ridx, l);
    // fused attention
    flash_attn<<<256, 256, 0, stream>>>(qbuf, kbuf, vTf, att);
    // TAG 3: x = x + O @ Wo + bo   (M=2048, N=1024)
    gemm_bt<3><<<dim3(8, 16), 256, 0, stream>>>(att, 1024, WoTl, 1024, 1.f,
        xf, bo_b + (size_t)l * 1024, xf, xbf, 1024, 1024);
    // FF1 hgl = x @ W1 + b1   (M=2048, N=8192) -- 256^2 tile kernel
    gemm256<<<dim3(32, 8), 512, 0, stream>>>(xbf, 1024, W1Tl, 1024,
        b1_b + (size_t)l * 8192, hgl, 8192, 1024);
    geglu_kernel<<<32768, 256, 0, stream>>>(hgl, ybuf);
    // FF2 split-K into partials (alias hgl, now dead) + fused reduce
    gemm_splitk<<<dim3(8, 16, 4), 256, 0, stream>>>(ybuf, 4096, W2Tl, 4096,
                                                    pbuf, 1024, 2048, 1024);
    reduce_ff2<<<8192, 256, 0, stream>>>(pbuf, b2_b + (size_t)l * 1024, xf, xbf);
  }

  emit_kernel<<<8192, 256, 0, stream>>>(xf, flag, d_out);
}

// Round 3
// 785.671 us; speedup vs baseline: 2.3575x; 1.0522x over previous
//
#include <hip/hip_runtime.h>
#include <hip/hip_bf16.h>
#include <math.h>

typedef __hip_bfloat16 bf16;
typedef __bf16 bf16x8 __attribute__((ext_vector_type(8)));
typedef float f32x4 __attribute__((ext_vector_type(4)));

typedef __attribute__((address_space(3))) void lds_void;
typedef const __attribute__((address_space(1))) void gbl_void;

__device__ __forceinline__ float b2f(bf16 v) { return __bfloat162float(v); }
__device__ __forceinline__ bf16 f2b(float v) { return __float2bfloat16(v); }

__device__ __forceinline__ f32x4 shfl_xor4(f32x4 v, int m) {
  f32x4 o;
  o[0] = __shfl_xor(v[0], m);
  o[1] = __shfl_xor(v[1], m);
  o[2] = __shfl_xor(v[2], m);
  o[3] = __shfl_xor(v[3], m);
  return o;
}
__device__ __forceinline__ f32x4 max4(f32x4 a, f32x4 b) {
  f32x4 o;
  o[0] = fmaxf(a[0], b[0]); o[1] = fmaxf(a[1], b[1]);
  o[2] = fmaxf(a[2], b[2]); o[3] = fmaxf(a[3], b[3]);
  return o;
}
__device__ __forceinline__ f32x4 exp4(f32x4 a) {
  f32x4 o;
  o[0] = __expf(a[0]); o[1] = __expf(a[1]);
  o[2] = __expf(a[2]); o[3] = __expf(a[3]);
  return o;
}

// ---------------------------------------------------------------------------
// dtype detection (inputs bf16 vs fp32), device-side, deterministic per call
// ---------------------------------------------------------------------------
__global__ void detect_dtype(const unsigned int* __restrict__ x, int* __restrict__ flag) {
  int cnt = 0;
  for (int i = 0; i < 128; ++i) {
    unsigned int lo = x[i] & 0xFFFFu;
    unsigned int e = (lo >> 7) & 0xFFu;
    if (e >= 100u && e <= 140u) ++cnt;
  }
  *flag = (cnt >= 96) ? 1 : 0;
}

__global__ void convert_in(const void* __restrict__ src, bf16* __restrict__ dst,
                           int n, const int* __restrict__ flag) {
  int i = blockIdx.x * 256 + threadIdx.x;
  if (i >= n) return;
  dst[i] = (*flag) ? ((const bf16*)src)[i] : f2b(((const float*)src)[i]);
}

__global__ void emit_kernel(const float* __restrict__ xf, const int* __restrict__ flag,
                            void* __restrict__ out) {
  int i = blockIdx.x * 256 + threadIdx.x;
  if (*flag) ((bf16*)out)[i] = f2b(xf[i]);
  else       ((float*)out)[i] = xf[i];
}

// ---------------------------------------------------------------------------
// 128^2-tile GEMM: C = alpha * A @ Bt^T (+bias +resid), bf16 in, fp32 acc.
// Double-buffered LDS, prefetch at tile start (global_load_lds w=16),
// ONE __syncthreads per K-tile. LDS XOR-swizzled (slot ^= row&7).
// ---------------------------------------------------------------------------
template<int TAG>
__global__ __launch_bounds__(256, 2) void gemm_bt(
    const bf16* __restrict__ A, int lda,
    const bf16* __restrict__ Bt, int ldb,
    float alpha,
    const float* __restrict__ resid,
    const bf16* __restrict__ bias,
    float* __restrict__ outf,
    bf16* __restrict__ outb,
    int ldc, int K)
{
  __shared__ char smem[65536] __attribute__((aligned(16)));
  float* lC = (float*)smem;            // epilogue alias (32 KB = 64x128 f32)

  int tid = threadIdx.x;
  int lane = tid & 63;
  int wave = tid >> 6;
  int quad = lane >> 4, l16 = lane & 15;
  int wm = (wave >> 1) * 64, wn = (wave & 1) * 64;
  int row0 = blockIdx.y * 128, col0 = blockIdx.x * 128;

  const bf16* asrc[4]; const bf16* bsrc[4];
#pragma unroll
  for (int i = 0; i < 4; ++i) {
    int row = i * 32 + (tid >> 3);
    int coff = ((tid & 7) * 16) ^ ((row & 7) << 4);   // bytes
    asrc[i] = A + (long long)(row0 + row) * lda + (coff >> 1);
    bsrc[i] = Bt + (long long)(col0 + row) * ldb + (coff >> 1);
  }
  int ldsbase = wave * 1024;

  f32x4 acc[4][4];
#pragma unroll
  for (int a = 0; a < 4; ++a)
#pragma unroll
    for (int b = 0; b < 4; ++b) acc[a][b] = (f32x4){0.f, 0.f, 0.f, 0.f};

  int nk = K >> 6;
#pragma unroll
  for (int i = 0; i < 4; ++i) {
    __builtin_amdgcn_global_load_lds((gbl_void*)(asrc[i]),
        (lds_void*)(smem + i * 4096 + ldsbase), 16, 0, 0);
    __builtin_amdgcn_global_load_lds((gbl_void*)(bsrc[i]),
        (lds_void*)(smem + 16384 + i * 4096 + ldsbase), 16, 0, 0);
  }
  __syncthreads();

  for (int t = 0; t < nk; ++t) {
    int buf = (t & 1) << 15;
    int nbuf = buf ^ 32768;
    if (t + 1 < nk) {
      int k0 = (t + 1) << 6;
#pragma unroll
      for (int i = 0; i < 4; ++i) {
        __builtin_amdgcn_global_load_lds((gbl_void*)(asrc[i] + k0),
            (lds_void*)(smem + nbuf + i * 4096 + ldsbase), 16, 0, 0);
        __builtin_amdgcn_global_load_lds((gbl_void*)(bsrc[i] + k0),
            (lds_void*)(smem + nbuf + 16384 + i * 4096 + ldsbase), 16, 0, 0);
      }
    }
    const __bf16* lA = (const __bf16*)(smem + buf);
    const __bf16* lB = (const __bf16*)(smem + buf + 16384);
#pragma unroll
    for (int ks = 0; ks < 2; ++ks) {
      bf16x8 af[4], bfr[4];
#pragma unroll
      for (int mi = 0; mi < 4; ++mi) {
        int r = wm + mi * 16 + l16;
        af[mi] = *(const bf16x8*)&lA[r * 64 + ((ks * 32 + quad * 8) ^ ((r & 7) << 3))];
      }
#pragma unroll
      for (int ni = 0; ni < 4; ++ni) {
        int r = wn + ni * 16 + l16;
        bfr[ni] = *(const bf16x8*)&lB[r * 64 + ((ks * 32 + quad * 8) ^ ((r & 7) << 3))];
      }
      __builtin_amdgcn_s_setprio(1);
#pragma unroll
      for (int mi = 0; mi < 4; ++mi)
#pragma unroll
        for (int ni = 0; ni < 4; ++ni)
          acc[mi][ni] = __builtin_amdgcn_mfma_f32_16x16x32_bf16(
              af[mi], bfr[ni], acc[mi][ni], 0, 0, 0);
      __builtin_amdgcn_s_setprio(0);
    }
    __syncthreads();
  }

  // --- LDS epilogue: two halves of 64 rows; full-line vectorized stores ---
#pragma unroll
  for (int half = 0; half < 2; ++half) {
    __syncthreads();
    if ((wave >> 1) == half) {
#pragma unroll
      for (int mi = 0; mi < 4; ++mi)
#pragma unroll
        for (int ni = 0; ni < 4; ++ni)
#pragma unroll
          for (int r = 0; r < 4; ++r)
            lC[(mi * 16 + quad * 4 + r) * 128 + wn + ni * 16 + l16] =
                acc[mi][ni][r] * alpha;
    }
    __syncthreads();
#pragma unroll
    for (int i = 0; i < 8; ++i) {
      int f = i * 256 + tid;             // 0..2047
      int row = f >> 5, cc = (f & 31) * 4;
      int m = row0 + half * 64 + row, n = col0 + cc;
      f32x4 v = *(const f32x4*)&lC[row * 128 + cc];
      long long ci = (long long)m * ldc + n;
      if (bias) {
        v[0] += b2f(bias[n]);     v[1] += b2f(bias[n + 1]);
        v[2] += b2f(bias[n + 2]); v[3] += b2f(bias[n + 3]);
      }
      if (resid) v += *(const f32x4*)&resid[ci];
      if (outf) *(f32x4*)&outf[ci] = v;
      if (outb) {
        bf16 c0 = f2b(v[0]), c1 = f2b(v[1]), c2 = f2b(v[2]), c3 = f2b(v[3]);
        ushort4 o = { *(unsigned short*)&c0, *(unsigned short*)&c1,
                      *(unsigned short*)&c2, *(unsigned short*)&c3 };
        *(ushort4*)&outb[ci] = o;
      }
    }
  }
}

// ---------------------------------------------------------------------------
// 256^2-tile GEMM (8 waves, 128 KB LDS dbuf) for big-N shapes (FF1).
// ---------------------------------------------------------------------------
__global__ __launch_bounds__(512, 2) void gemm256(
    const bf16* __restrict__ A, int lda,
    const bf16* __restrict__ Bt, int ldb,
    const bf16* __restrict__ bias,
    bf16* __restrict__ outb,
    int ldc, int K)
{
  __shared__ char smem[131072] __attribute__((aligned(16)));
  float* lC = (float*)smem;

  int tid = threadIdx.x;
  int lane = tid & 63;
  int wave = tid >> 6;
  int quad = lane >> 4, l16 = lane & 15;
  int wr = wave >> 2, wc = wave & 3;
  int wm = wr * 128, wn = wc * 64;
  int row0 = blockIdx.y * 256, col0 = blockIdx.x * 256;

  const bf16* asrc[4]; const bf16* bsrc[4];
#pragma unroll
  for (int i = 0; i < 4; ++i) {
    int row = i * 64 + (tid >> 3);
    int coff = ((tid & 7) * 16) ^ ((row & 7) << 4);
    asrc[i] = A + (long long)(row0 + row) * lda + (coff >> 1);
    bsrc[i] = Bt + (long long)(col0 + row) * ldb + (coff >> 1);
  }
  int ldsbase = wave * 1024;

  f32x4 acc[8][4];
#pragma unroll
  for (int a = 0; a < 8; ++a)
#pragma unroll
    for (int b = 0; b < 4; ++b) acc[a][b] = (f32x4){0.f, 0.f, 0.f, 0.f};

  int nk = K >> 6;
#pragma unroll
  for (int i = 0; i < 4; ++i) {
    __builtin_amdgcn_global_load_lds((gbl_void*)(asrc[i]),
        (lds_void*)(smem + i * 8192 + ldsbase), 16, 0, 0);
    __builtin_amdgcn_global_load_lds((gbl_void*)(bsrc[i]),
        (lds_void*)(smem + 32768 + i * 8192 + ldsbase), 16, 0, 0);
  }
  __syncthreads();

  for (int t = 0; t < nk; ++t) {
    int buf = (t & 1) << 16;
    int nbuf = buf ^ 65536;
    if (t + 1 < nk) {
      int k0 = (t + 1) << 6;
#pragma unroll
      for (int i = 0; i < 4; ++i) {
        __builtin_amdgcn_global_load_lds((gbl_void*)(asrc[i] + k0),
            (lds_void*)(smem + nbuf + i * 8192 + ldsbase), 16, 0, 0);
        __builtin_amdgcn_global_load_lds((gbl_void*)(bsrc[i] + k0),
            (lds_void*)(smem + nbuf + 32768 + i * 8192 + ldsbase), 16, 0, 0);
      }
    }
    const __bf16* lA = (const __bf16*)(smem + buf);
    const __bf16* lB = (const __bf16*)(smem + buf + 32768);
#pragma unroll
    for (int ks = 0; ks < 2; ++ks) {
      bf16x8 af[8], bfr[4];
#pragma unroll
      for (int mi = 0; mi < 8; ++mi) {
        int r = wm + mi * 16 + l16;
        af[mi] = *(const bf16x8*)&lA[r * 64 + ((ks * 32 + quad * 8) ^ ((r & 7) << 3))];
      }
#pragma unroll
      for (int ni = 0; ni < 4; ++ni) {
        int r = wn + ni * 16 + l16;
        bfr[ni] = *(const bf16x8*)&lB[r * 64 + ((ks * 32 + quad * 8) ^ ((r & 7) << 3))];
      }
      __builtin_amdgcn_s_setprio(1);
#pragma unroll
      for (int mi = 0; mi < 8; ++mi)
#pragma unroll
        for (int ni = 0; ni < 4; ++ni)
          acc[mi][ni] = __builtin_amdgcn_mfma_f32_16x16x32_bf16(
              af[mi], bfr[ni], acc[mi][ni], 0, 0, 0);
      __builtin_amdgcn_s_setprio(0);
    }
    __syncthreads();
  }

#pragma unroll
  for (int h = 0; h < 2; ++h) {
    __syncthreads();
    if (wr == h) {
#pragma unroll
      for (int mi = 0; mi < 8; ++mi)
#pragma unroll
        for (int ni = 0; ni < 4; ++ni)
#pragma unroll
          for (int r = 0; r < 4; ++r)
            lC[(mi * 16 + quad * 4 + r) * 256 + wn + ni * 16 + l16] =
                acc[mi][ni][r];
    }
    __syncthreads();
#pragma unroll
    for (int it = 0; it < 16; ++it) {
      int f = it * 512 + tid;
      int row = f >> 6, cc = (f & 63) * 4;
      int m = row0 + h * 128 + row, n = col0 + cc;
      f32x4 v = *(const f32x4*)&lC[row * 256 + cc];
      v[0] += b2f(bias[n]);     v[1] += b2f(bias[n + 1]);
      v[2] += b2f(bias[n + 2]); v[3] += b2f(bias[n + 3]);
      bf16 c0 = f2b(v[0]), c1 = f2b(v[1]), c2 = f2b(v[2]), c3 = f2b(v[3]);
      ushort4 o = { *(unsigned short*)&c0, *(unsigned short*)&c1,
                    *(unsigned short*)&c2, *(unsigned short*)&c3 };
      *(ushort4*)&outb[(long long)m * ldc + n] = o;
    }
  }
}

// ---------------------------------------------------------------------------
// Split-K GEMM: pbuf[z][m][n] = A(K-chunk z) @ Bt^T. Same dbuf+swizzle.
// ---------------------------------------------------------------------------
__global__ __launch_bounds__(256, 2) void gemm_splitk(
    const bf16* __restrict__ A, int lda,
    const bf16* __restrict__ Bt, int ldb,
    float* __restrict__ pbuf, int ldc, int M, int KC)
{
  __shared__ char smem[65536] __attribute__((aligned(16)));

  int koff = blockIdx.z * KC;
  float* outz = pbuf + (long long)blockIdx.z * M * ldc;
  int tid = threadIdx.x;
  int lane = tid & 63;
  int wave = tid >> 6;
  int quad = lane >> 4, l16 = lane & 15;
  int wm = (wave >> 1) * 64, wn = (wave & 1) * 64;
  int row0 = blockIdx.y * 128, col0 = blockIdx.x * 128;

  const bf16* asrc[4]; const bf16* bsrc[4];
#pragma unroll
  for (int i = 0; i < 4; ++i) {
    int row = i * 32 + (tid >> 3);
    int coff = ((tid & 7) * 16) ^ ((row & 7) << 4);
    asrc[i] = A + (long long)(row0 + row) * lda + koff + (coff >> 1);
    bsrc[i] = Bt + (long long)(col0 + row) * ldb + koff + (coff >> 1);
  }
  int ldsbase = wave * 1024;

  f32x4 acc[4][4];
#pragma unroll
  for (int a = 0; a < 4; ++a)
#pragma unroll
    for (int b = 0; b < 4; ++b) acc[a][b] = (f32x4){0.f, 0.f, 0.f, 0.f};

  int nk = KC >> 6;
#pragma unroll
  for (int i = 0; i < 4; ++i) {
    __builtin_amdgcn_global_load_lds((gbl_void*)(asrc[i]),
        (lds_void*)(smem + i * 4096 + ldsbase), 16, 0, 0);
    __builtin_amdgcn_global_load_lds((gbl_void*)(bsrc[i]),
        (lds_void*)(smem + 16384 + i * 4096 + ldsbase), 16, 0, 0);
  }
  __syncthreads();

  for (int t = 0; t < nk; ++t) {
    int buf = (t & 1) << 15;
    int nbuf = buf ^ 32768;
    if (t + 1 < nk) {
      int k0 = (t + 1) << 6;
#pragma unroll
      for (int i = 0; i < 4; ++i) {
        __builtin_amdgcn_global_load_lds((gbl_void*)(asrc[i] + k0),
            (lds_void*)(smem + nbuf + i * 4096 + ldsbase), 16, 0, 0);
        __builtin_amdgcn_global_load_lds((gbl_void*)(bsrc[i] + k0),
            (lds_void*)(smem + nbuf + 16384 + i * 4096 + ldsbase), 16, 0, 0);
      }
    }
    const __bf16* lA = (const __bf16*)(smem + buf);
    const __bf16* lB = (const __bf16*)(smem + buf + 16384);
#pragma unroll
    for (int ks = 0; ks < 2; ++ks) {
      bf16x8 af[4], bfr[4];
#pragma unroll
      for (int mi = 0; mi < 4; ++mi) {
        int r = wm + mi * 16 + l16;
        af[mi] = *(const bf16x8*)&lA[r * 64 + ((ks * 32 + quad * 8) ^ ((r & 7) << 3))];
      }
#pragma unroll
      for (int ni = 0; ni < 4; ++ni) {
        int r = wn + ni * 16 + l16;
        bfr[ni] = *(const bf16x8*)&lB[r * 64 + ((ks * 32 + quad * 8) ^ ((r & 7) << 3))];
      }
      __builtin_amdgcn_s_setprio(1);
#pragma unroll
      for (int mi = 0; mi < 4; ++mi)
#pragma unroll
        for (int ni = 0; ni < 4; ++ni)
          acc[mi][ni] = __builtin_amdgcn_mfma_f32_16x16x32_bf16(
              af[mi], bfr[ni], acc[mi][ni], 0, 0, 0);
      __builtin_amdgcn_s_setprio(0);
    }
    __syncthreads();
  }

#pragma unroll
  for (int mi = 0; mi < 4; ++mi)
#pragma unroll
    for (int ni = 0; ni < 4; ++ni) {
      int n = col0 + wn + ni * 16 + l16;
#pragma unroll
      for (int r = 0; r < 4; ++r) {
        int m = row0 + wm + mi * 16 + quad * 4 + r;
        outz[(long long)m * ldc + n] = acc[mi][ni][r];
      }
    }
}

// reduce 4 split-K partials + b2 + residual -> xf (fp32) and xbf (bf16)
__global__ void reduce_ff2(const float* __restrict__ pbuf, const bf16* __restrict__ bias,
                           float* __restrict__ xf, bf16* __restrict__ xbf) {
  int i = blockIdx.x * 256 + threadIdx.x;   // [0, 2048*1024)
  const int NT = 2048 * 1024;
  float v = xf[i] + b2f(bias[i & 1023]) +
            pbuf[i] + pbuf[i + NT] + pbuf[i + 2 * NT] + pbuf[i + 3 * NT];
  xf[i] = v;
  xbf[i] = f2b(v);
}

// ---------------------------------------------------------------------------
// Fused flash attention, v2: 8 waves x 16 q-rows, dbuf global_load_lds
// staging with XOR swizzle, prefetch-at-loop-top, ONE barrier per K/V tile.
// LDS: K dbuf [0,32768), V dbuf [32768,65536), P-scratch [65536,75776).
// ---------------------------------------------------------------------------
__device__ __forceinline__ void fa_stage(
    const bf16* __restrict__ kb, const bf16* __restrict__ vtb, int j0, int tk,
    char* smem, int kboff, int vboff, int tid, int wave)
{
  int rounds = tk >> 6;
  for (int i = 0; i < rounds; ++i) {
    // K tile: tk rows x 128 B (d=64), linear LDS, inverse-swizzled source
    int rowk = i * 64 + (tid >> 3);
    int cbk = ((tid & 7) * 16) ^ ((rowk & 7) << 4);
    __builtin_amdgcn_global_load_lds(
        (gbl_void*)(kb + (long long)(j0 + rowk) * 1024 + (cbk >> 1)),
        (lds_void*)(smem + kboff + i * 8192 + wave * 1024), 16, 0, 0);
    // V tile: 64 rows x tk*2 B
    int rowv, cbv;
    if (tk == 128) { rowv = i * 32 + (tid >> 4); cbv = ((tid & 15) * 16) ^ ((rowv & 7) << 4); }
    else           { rowv = (tid >> 3);          cbv = ((tid & 7) * 16) ^ ((rowv & 7) << 4); }
    __builtin_amdgcn_global_load_lds(
        (gbl_void*)(vtb + (long long)rowv * 8704 + j0 + (cbv >> 1)),
        (lds_void*)(smem + vboff + i * 8192 + wave * 1024), 16, 0, 0);
  }
}

template<int TK>
__device__ __forceinline__ void fa_compute(
    const char* smem, int kboff, int vboff,
    const bf16x8 (&qa)[2], bf16* lPw,
    int quad, int l16,
    f32x4 (&accO)[4], f32x4& mrow, f32x4& lrow)
{
  constexpr int NT = TK / 16;
  constexpr int NCH = TK / 32;
  const __bf16* lK = (const __bf16*)(smem + kboff);
  const __bf16* lV = (const __bf16*)(smem + vboff);
  int xork = (l16 & 7) << 3;   // element-XOR, lane-uniform

  f32x4 accS[NT];
#pragma unroll
  for (int ni = 0; ni < NT; ++ni) accS[ni] = (f32x4){0.f, 0.f, 0.f, 0.f};

#pragma unroll
  for (int ni = 0; ni < NT; ++ni)
#pragma unroll
    for (int ks = 0; ks < 2; ++ks) {
      bf16x8 bfr = *(const bf16x8*)&lK[(ni * 16 + l16) * 64 + ((ks * 32 + quad * 8) ^ xork)];
      accS[ni] = __builtin_amdgcn_mfma_f32_16x16x32_bf16(qa[ks], bfr, accS[ni], 0, 0, 0);
    }

  // online softmax (rows = quad*4+r, cols distributed over l16 x ni)
  f32x4 vmax = (f32x4){-INFINITY, -INFINITY, -INFINITY, -INFINITY};
#pragma unroll
  for (int ni = 0; ni < NT; ++ni) {
    accS[ni] *= 0.125f;
    vmax = max4(vmax, accS[ni]);
  }
#pragma unroll
  for (int m = 1; m <= 8; m <<= 1) vmax = max4(vmax, shfl_xor4(vmax, m));
  f32x4 mnew = max4(mrow, vmax);
  f32x4 alpha = exp4(mrow - mnew);
  f32x4 rs = (f32x4){0.f, 0.f, 0.f, 0.f};
#pragma unroll
  for (int ni = 0; ni < NT; ++ni) {
    accS[ni] = exp4(accS[ni] - mnew);
    rs += accS[ni];
  }
#pragma unroll
  for (int m = 1; m <= 8; m <<= 1) rs += shfl_xor4(rs, m);
  lrow = lrow * alpha + rs;
  mrow = mnew;
#pragma unroll
  for (int nd = 0; nd < 4; ++nd) accO[nd] *= alpha;

  // PV: per 32-col chunk, stage P (16x32) in per-wave LDS, MFMA against V
#pragma unroll
  for (int c = 0; c < NCH; ++c) {
#pragma unroll
    for (int u = 0; u < 2; ++u)
#pragma unroll
      for (int r = 0; r < 4; ++r)
        lPw[(quad * 4 + r) * 40 + u * 16 + l16] = f2b(accS[c * 2 + u][r]);
    bf16x8 pa = *(const bf16x8*)&lPw[l16 * 40 + quad * 8];
#pragma unroll
    for (int nd = 0; nd < 4; ++nd) {
      bf16x8 vb = *(const bf16x8*)&lV[(nd * 16 + l16) * TK + ((c * 32 + quad * 8) ^ xork)];
      accO[nd] = __builtin_amdgcn_mfma_f32_16x16x32_bf16(pa, vb, accO[nd], 0, 0, 0);
    }
  }
}

__global__ __launch_bounds__(512, 2) void flash_attn(
    const bf16* __restrict__ q, const bf16* __restrict__ k,
    const bf16* __restrict__ vt, bf16* __restrict__ att)
{
  __shared__ char smem[75776] __attribute__((aligned(16)));

  int idx = blockIdx.x;
  int b = idx >> 5, h = (idx >> 1) & 15, half = idx & 1;
  int tid = threadIdx.x, wave = tid >> 6, lane = tid & 63;
  int quad = lane >> 4, l16 = lane & 15;
  int qrow0 = b * 256 + half * 128 + wave * 16;

  const bf16* kb  = k  + (long long)b * 1088 * 1024 + h * 64;
  const bf16* vtb = vt + (long long)(h * 64) * 8704 + b * 1088;
  bf16* lPw = (bf16*)(smem + 65536 + wave * 1280);

  bf16x8 qa[2];
#pragma unroll
  for (int ks = 0; ks < 2; ++ks)
    qa[ks] = *(const bf16x8*)&q[(long long)(qrow0 + l16) * 1024 +
                                h * 64 + ks * 32 + quad * 8];

  f32x4 accO[4];
  f32x4 mrow = (f32x4){-INFINITY, -INFINITY, -INFINITY, -INFINITY};
  f32x4 lrow = (f32x4){0.f, 0.f, 0.f, 0.f};
#pragma unroll
  for (int nd = 0; nd < 4; ++nd) accO[nd] = (f32x4){0.f, 0.f, 0.f, 0.f};

  // prologue: stage tile 0 into buffer 0
  fa_stage(kb, vtb, 0, 128, smem, 0, 32768, tid, wave);
  __syncthreads();

  for (int jt = 0; jt < 8; ++jt) {
    int buf = (jt & 1) * 16384;
    int nbuf = 16384 - buf;
    if (jt < 7) fa_stage(kb, vtb, (jt + 1) * 128, 128, smem, nbuf, 32768 + nbuf, tid, wave);
    else        fa_stage(kb, vtb, 1024, 64, smem, nbuf, 32768 + nbuf, tid, wave);
    fa_compute<128>(smem, buf, 32768 + buf, qa, lPw, quad, l16, accO, mrow, lrow);
    __syncthreads();
  }
  // tail tile 8 (64 rows) sits in buffer (8&1)==0
  fa_compute<64>(smem, 0, 32768, qa, lPw, quad, l16, accO, mrow, lrow);

  f32x4 inv;
  inv[0] = 1.f / lrow[0]; inv[1] = 1.f / lrow[1];
  inv[2] = 1.f / lrow[2]; inv[3] = 1.f / lrow[3];
#pragma unroll
  for (int nd = 0; nd < 4; ++nd) {
    f32x4 o = accO[nd] * inv;
#pragma unroll
    for (int r = 0; r < 4; ++r)
      att[(long long)(qrow0 + quad * 4 + r) * 1024 +
          h * 64 + nd * 16 + l16] = f2b(o[r]);
  }
}

// ---------------------------------------------------------------------------
// Elementwise / helper kernels
// ---------------------------------------------------------------------------
__global__ void init_x_kernel(const void* __restrict__ x, const int* __restrict__ flag,
                              float* __restrict__ xf, bf16* __restrict__ xbf) {
  int i = blockIdx.x * 256 + threadIdx.x;
  float v = (*flag) ? b2f(((const bf16*)x)[i]) : ((const float*)x)[i];
  xf[i] = v;
  xbf[i] = f2b(v);
}

__global__ void transpose_w(const void* __restrict__ in, bf16* __restrict__ out,
                            int R, int C, const int* __restrict__ flag) {
  __shared__ bf16 tile[32][33];
  long long zoff = (long long)blockIdx.z * R * C;
  const bf16* inb = (const bf16*)in + zoff;
  const float* inf = (const float*)in + zoff;
  out += zoff;
  int tx = threadIdx.x, ty = threadIdx.y;
  int c0 = blockIdx.x * 32, r0 = blockIdx.y * 32;
  int isb = *flag;
#pragma unroll
  for (int i = 0; i < 4; ++i) {
    long long off = (long long)(r0 + ty + i * 8) * C + (c0 + tx);
    tile[ty + i * 8][tx] = isb ? inb[off] : f2b(inf[off]);
  }
  __syncthreads();
#pragma unroll
  for (int i = 0; i < 4; ++i)
    out[(long long)(c0 + ty + i * 8) * R + (r0 + tx)] = tile[tx][ty + i * 8];
}

__global__ void rotary_q_kernel(bf16* __restrict__ q, const bf16* __restrict__ srcf) {
  int idx = blockIdx.x * 256 + threadIdx.x;
  int row = idx >> 9;
  int p = idx & 511;
  int h = p >> 5, i = p & 31;
  int d0 = h * 64 + 2 * i;
  int ntok = row & 255;
  float f = b2f(srcf[ntok * 64 + 2 * i]);
  float c = cosf(f), s = sinf(f);
  long long base = (long long)row * 1024 + d0;
  float q0 = b2f(q[base]), q1 = b2f(q[base + 1]);
  q[base]     = f2b(q0 * c - q1 * s);
  q[base + 1] = f2b(q1 * c + q0 * s);
}

__global__ void k_bias_rot_kernel(bf16* __restrict__ k, const bf16* __restrict__ tgtf,
                                  const bf16* __restrict__ rpe,
                                  const int* __restrict__ ridx, int layer) {
  int idx = blockIdx.x * 256 + threadIdx.x;
  int b = idx >> 19;
  int rem = idx & ((1 << 19) - 1);
  int j = rem >> 9;
  int p = rem & 511;
  int h = p >> 5, i = p & 31;
  int d0 = h * 64 + 2 * i;
  float bias = b2f(rpe[(layer * 405 + ridx[j >> 8]) * 16 + h]);
  float f = b2f(tgtf[j * 64 + 2 * i]);
  float c = cosf(f), s = sinf(f);
  long long base = (long long)(b * 1088 + j) * 1024 + d0;
  float k0 = b2f(k[base]) + bias, k1 = b2f(k[base + 1]) + bias;
  k[base]     = f2b(k0 * c - k1 * s);
  k[base + 1] = f2b(k1 * c + k0 * s);
}

__global__ void geglu_kernel(const bf16* __restrict__ hgl, bf16* __restrict__ y) {
  int idx = blockIdx.x * 256 + threadIdx.x;
  int m = idx >> 12, n = idx & 4095;
  float a = b2f(hgl[(long long)m * 8192 + n]);
  float g = b2f(hgl[(long long)m * 8192 + 4096 + n]);
  float ge = 0.5f * g * (1.0f + erff(g * 0.70710678118654752f));
  y[idx] = f2b(a * ge);
}

// ---------------------------------------------------------------------------
extern "C" void kernel_launch(void* const* d_in, const int* in_sizes, int n_in,
                              void* d_out, int out_size, void* d_ws, size_t ws_size,
                              hipStream_t stream) {
  (void)in_sizes; (void)n_in; (void)out_size; (void)ws_size;
  const void* x    = d_in[0];
  const void* cond = d_in[1];
  const void* Wq   = d_in[2];
  const void* Wk   = d_in[3];
  const void* Wv   = d_in[4];
  const void* Wo   = d_in[5];
  const void* bo   = d_in[6];
  const void* rpe  = d_in[7];
  const void* W1   = d_in[8];
  const void* b1   = d_in[9];
  const void* W2   = d_in[10];
  const void* b2   = d_in[11];
  const void* srcf = d_in[12];
  const void* tgtf = d_in[13];
  const int*  ridx = (const int*)d_in[14];

  char* w = (char*)d_ws;
  int* flag = (int*)w;   w += 256;
  bf16* WqT = (bf16*)w;  w += (size_t)2 * 1024 * 1024 * 2;
  bf16* WkT = (bf16*)w;  w += (size_t)2 * 1024 * 1024 * 2;
  bf16* WvT = (bf16*)w;  w += (size_t)2 * 1024 * 1024 * 2;
  bf16* WoT = (bf16*)w;  w += (size_t)2 * 1024 * 1024 * 2;
  bf16* W1T = (bf16*)w;  w += (size_t)2 * 8192 * 1024 * 2;
  bf16* W2T = (bf16*)w;  w += (size_t)2 * 4096 * 1024 * 2;
  bf16* condb = (bf16*)w; w += (size_t)8704 * 1024 * 2;
  bf16* bo_b = (bf16*)w;  w += 2048 * 2;
  bf16* rpe_b = (bf16*)w; w += 12960 * 2;
  bf16* b1_b = (bf16*)w;  w += 16384 * 2;
  bf16* b2_b = (bf16*)w;  w += 2048 * 2;
  bf16* srcf_b = (bf16*)w; w += 16384 * 2;
  bf16* tgtf_b = (bf16*)w; w += 65536 * 2;
  float* xf = (float*)w; w += (size_t)2048 * 1024 * 4;
  bf16* xbf = (bf16*)w;  w += (size_t)2048 * 1024 * 2;
  bf16* qbuf = (bf16*)w; w += (size_t)2048 * 1024 * 2;
  bf16* kbuf = (bf16*)w; w += (size_t)8704 * 1024 * 2;
  bf16* vTf = (bf16*)w;  w += (size_t)1024 * 8704 * 2;
  bf16* att = (bf16*)w;  w += (size_t)2048 * 1024 * 2;
  bf16* hgl = (bf16*)w;  w += (size_t)2048 * 8192 * 2;   // 32 MiB
  bf16* ybuf = (bf16*)w; w += (size_t)2048 * 4096 * 2;   // 16 MiB
  float* pbuf = (float*)hgl;  // split-K partials (4 x 8 MiB) alias dead hgl

  detect_dtype<<<1, 1, 0, stream>>>((const unsigned int*)x, flag);

  convert_in<<<34816, 256, 0, stream>>>(cond, condb, 8704 * 1024, flag);
  convert_in<<<8, 256, 0, stream>>>(bo, bo_b, 2048, flag);
  convert_in<<<51, 256, 0, stream>>>(rpe, rpe_b, 12960, flag);
  convert_in<<<64, 256, 0, stream>>>(b1, b1_b, 16384, flag);
  convert_in<<<8, 256, 0, stream>>>(b2, b2_b, 2048, flag);
  convert_in<<<64, 256, 0, stream>>>(srcf, srcf_b, 16384, flag);
  convert_in<<<256, 256, 0, stream>>>(tgtf, tgtf_b, 65536, flag);

  dim3 tb(32, 8);
  transpose_w<<<dim3(32, 32, 2),  tb, 0, stream>>>(Wq, WqT, 1024, 1024, flag);
  transpose_w<<<dim3(32, 32, 2),  tb, 0, stream>>>(Wk, WkT, 1024, 1024, flag);
  transpose_w<<<dim3(32, 32, 2),  tb, 0, stream>>>(Wv, WvT, 1024, 1024, flag);
  transpose_w<<<dim3(32, 32, 2),  tb, 0, stream>>>(Wo, WoT, 1024, 1024, flag);
  transpose_w<<<dim3(256, 32, 2), tb, 0, stream>>>(W1, W1T, 1024, 8192, flag);
  transpose_w<<<dim3(32, 128, 2), tb, 0, stream>>>(W2, W2T, 4096, 1024, flag);
  init_x_kernel<<<8192, 256, 0, stream>>>(x, flag, xf, xbf);

  for (int l = 0; l < 2; ++l) {
    const bf16* WqTl = WqT + (size_t)l * 1024 * 1024;
    const bf16* WkTl = WkT + (size_t)l * 1024 * 1024;
    const bf16* WvTl = WvT + (size_t)l * 1024 * 1024;
    const bf16* WoTl = WoT + (size_t)l * 1024 * 1024;
    const bf16* W1Tl = W1T + (size_t)l * 8192 * 1024;
    const bf16* W2Tl = W2T + (size_t)l * 4096 * 1024;

    // TAG 0: q = x @ Wq   (M=2048, N=1024)
    gemm_bt<0><<<dim3(8, 16), 256, 0, stream>>>(xbf, 1024, WqTl, 1024, 1.f,
        nullptr, nullptr, nullptr, qbuf, 1024, 1024);
    rotary_q_kernel<<<4096, 256, 0, stream>>>(qbuf, srcf_b);
    // TAG 1: V^T = Wv^T @ cond^T   (M=1024, N=8704)
    gemm_bt<1><<<dim3(68, 8), 256, 0, stream>>>(WvTl, 1024, condb, 1024, 1.f,
        nullptr, nullptr, nullptr, vTf, 8704, 1024);
    // TAG 2: k = cond @ Wk   (M=8704, N=1024)
    gemm_bt<2><<<dim3(8, 68), 256, 0, stream>>>(condb, 1024, WkTl, 1024, 1.f,
        nullptr, nullptr, nullptr, kbuf, 1024, 1024);
    k_bias_rot_kernel<<<16384, 256, 0, stream>>>(kbuf, tgtf_b, rpe_b, ridx, l);
    // fused attention (8 waves x 16 q-rows, dbuf prefetch)
    flash_attn<<<256, 512, 0, stream>>>(qbuf, kbuf, vTf, att);
    // TAG 3: x = x + O @ Wo + bo   (M=2048, N=1024)
    gemm_bt<3><<<dim3(8, 16), 256, 0, stream>>>(att, 1024, WoTl, 1024, 1.f,
        xf, bo_b + (size_t)l * 1024, xf, xbf, 1024, 1024);
    // FF1 hgl = x @ W1 + b1   (M=2048, N=8192) -- 256^2 tile kernel
    gemm256<<<dim3(32, 8), 512, 0, stream>>>(xbf, 1024, W1Tl, 1024,
        b1_b + (size_t)l * 8192, hgl, 8192, 1024);
    geglu_kernel<<<32768, 256, 0, stream>>>(hgl, ybuf);
    // FF2 split-K into partials (alias hgl, now dead) + fused reduce
    gemm_splitk<<<dim3(8, 16, 4), 256, 0, stream>>>(ybuf, 4096, W2Tl, 4096,
                                                    pbuf, 1024, 2048, 1024);
    reduce_ff2<<<8192, 256, 0, stream>>>(pbuf, b2_b + (size_t)l * 1024, xf, xbf);
  }

  emit_kernel<<<8192, 256, 0, stream>>>(xf, flag, d_out);
}

// Round 4
// 783.906 us; speedup vs baseline: 2.3628x; 1.0023x over previous
//
#include <hip/hip_runtime.h>
#include <hip/hip_bf16.h>
#include <math.h>

typedef __hip_bfloat16 bf16;
typedef __bf16 bf16x8 __attribute__((ext_vector_type(8)));
typedef float f32x4 __attribute__((ext_vector_type(4)));

typedef __attribute__((address_space(3))) void lds_void;
typedef const __attribute__((address_space(1))) void gbl_void;

__device__ __forceinline__ float b2f(bf16 v) { return __bfloat162float(v); }
__device__ __forceinline__ bf16 f2b(float v) { return __float2bfloat16(v); }

__device__ __forceinline__ f32x4 shfl_xor4(f32x4 v, int m) {
  f32x4 o;
  o[0] = __shfl_xor(v[0], m);
  o[1] = __shfl_xor(v[1], m);
  o[2] = __shfl_xor(v[2], m);
  o[3] = __shfl_xor(v[3], m);
  return o;
}
__device__ __forceinline__ f32x4 max4(f32x4 a, f32x4 b) {
  f32x4 o;
  o[0] = fmaxf(a[0], b[0]); o[1] = fmaxf(a[1], b[1]);
  o[2] = fmaxf(a[2], b[2]); o[3] = fmaxf(a[3], b[3]);
  return o;
}
__device__ __forceinline__ f32x4 exp4(f32x4 a) {
  f32x4 o;
  o[0] = __expf(a[0]); o[1] = __expf(a[1]);
  o[2] = __expf(a[2]); o[3] = __expf(a[3]);
  return o;
}

// counted-vmcnt barrier: keep `ahead` prefetch batches (4 loads each) in
// flight across the barrier; drain everything older. Never 0 mid-loop (T4).
__device__ __forceinline__ void cbar(int ahead) {
  if (ahead >= 2)      asm volatile("s_waitcnt vmcnt(8)" ::: "memory");
  else if (ahead == 1) asm volatile("s_waitcnt vmcnt(4)" ::: "memory");
  else                 asm volatile("s_waitcnt vmcnt(0)" ::: "memory");
  __builtin_amdgcn_s_barrier();
  __builtin_amdgcn_sched_barrier(0);
}

// ---------------------------------------------------------------------------
// dtype detection (inputs bf16 vs fp32), device-side, deterministic per call
// ---------------------------------------------------------------------------
__global__ void detect_dtype(const unsigned int* __restrict__ x, int* __restrict__ flag) {
  int cnt = 0;
  for (int i = 0; i < 128; ++i) {
    unsigned int lo = x[i] & 0xFFFFu;
    unsigned int e = (lo >> 7) & 0xFFu;
    if (e >= 100u && e <= 140u) ++cnt;
  }
  *flag = (cnt >= 96) ? 1 : 0;
}

__global__ void convert_in(const void* __restrict__ src, bf16* __restrict__ dst,
                           int n, const int* __restrict__ flag) {
  int i = blockIdx.x * 256 + threadIdx.x;
  if (i >= n) return;
  dst[i] = (*flag) ? ((const bf16*)src)[i] : f2b(((const float*)src)[i]);
}

__global__ void emit_kernel(const float* __restrict__ xf, const int* __restrict__ flag,
                            void* __restrict__ out) {
  int i = blockIdx.x * 256 + threadIdx.x;
  if (*flag) ((bf16*)out)[i] = f2b(xf[i]);
  else       ((float*)out)[i] = xf[i];
}

// ---------------------------------------------------------------------------
// LDS K-tile layout (BK=32): a [2*HALF rows][32 k] bf16 tile packed as
// HALF lines x 128B; logical (r,kslot) sits at line (r & (HALF-1)),
// 16B-slot (((r>>LB)<<2)|kslot) ^ (line&7).  Same ds_read address structure
// as the round-3 (measured conflict-clean) BK=64 scheme.  Staging writes
// linearly (global_load_lds); the inverse map is applied to the SOURCE.
// ---------------------------------------------------------------------------
template<int HALF>
__device__ __forceinline__ bf16x8 frag_ld(const __bf16* lt, int r, int quad) {
  constexpr int LB = (HALF == 128) ? 7 : 6;
  int line = r & (HALF - 1);
  int sl = (((r >> LB) << 2) | quad) ^ (line & 7);
  return *(const bf16x8*)&lt[line * 64 + sl * 8];
}

// ---------------------------------------------------------------------------
// 128^2-tile GEMM, BK=32, quad-buffered LDS, prefetch depth 3, counted vmcnt.
// C = alpha * A @ Bt^T (+bias +resid), bf16 in, fp32 acc.
// ---------------------------------------------------------------------------
template<int TAG>
__global__ __launch_bounds__(256, 2) void gemm_bt(
    const bf16* __restrict__ A, int lda,
    const bf16* __restrict__ Bt, int ldb,
    float alpha,
    const float* __restrict__ resid,
    const bf16* __restrict__ bias,
    float* __restrict__ outf,
    bf16* __restrict__ outb,
    int ldc, int K)
{
  __shared__ char smem[65536] __attribute__((aligned(16)));
  float* lC = (float*)smem;            // epilogue alias (32 KB = 64x128 f32)

  int tid = threadIdx.x;
  int lane = tid & 63;
  int wave = tid >> 6;
  int quad = lane >> 4, l16 = lane & 15;
  int wm = (wave >> 1) * 64, wn = (wave & 1) * 64;
  int row0 = blockIdx.y * 128, col0 = blockIdx.x * 128;

  // staging source coords (inverse of frag_ld map), HALF=64, 2 rounds
  const bf16* asrc[2]; const bf16* bsrc[2];
#pragma unroll
  for (int i = 0; i < 2; ++i) {
    int line = i * 32 + (tid >> 3);
    int hx = (tid & 7) ^ (line & 7);
    int r = line + ((hx >> 2) << 6);
    int ke = (hx & 3) << 3;
    asrc[i] = A + (long long)(row0 + r) * lda + ke;
    bsrc[i] = Bt + (long long)(col0 + r) * ldb + ke;
  }

  auto stage = [&](int b, int t) {
    int o = t * 32;
#pragma unroll
    for (int i = 0; i < 2; ++i) {
      __builtin_amdgcn_global_load_lds((gbl_void*)(asrc[i] + o),
          (lds_void*)(smem + b * 8192 + i * 4096 + wave * 1024), 16, 0, 0);
      __builtin_amdgcn_global_load_lds((gbl_void*)(bsrc[i] + o),
          (lds_void*)(smem + 32768 + b * 8192 + i * 4096 + wave * 1024), 16, 0, 0);
    }
  };

  f32x4 acc[4][4];
#pragma unroll
  for (int a = 0; a < 4; ++a)
#pragma unroll
    for (int b = 0; b < 4; ++b) acc[a][b] = (f32x4){0.f, 0.f, 0.f, 0.f};

  int nk = K >> 5;                      // BK=32 tiles, nk >= 8 always
  stage(0, 0); stage(1, 1); stage(2, 2);
  cbar(2);                              // drain batch 0 only

  for (int t = 0; t < nk; ++t) {
    if (t + 3 < nk) stage((t + 3) & 3, t + 3);
    const __bf16* lA = (const __bf16*)(smem + (t & 3) * 8192);
    const __bf16* lB = (const __bf16*)(smem + 32768 + (t & 3) * 8192);
    bf16x8 af[4], bfr[4];
#pragma unroll
    for (int mi = 0; mi < 4; ++mi) af[mi] = frag_ld<64>(lA, wm + mi * 16 + l16, quad);
#pragma unroll
    for (int ni = 0; ni < 4; ++ni) bfr[ni] = frag_ld<64>(lB, wn + ni * 16 + l16, quad);
    __builtin_amdgcn_s_setprio(1);
#pragma unroll
    for (int mi = 0; mi < 4; ++mi)
#pragma unroll
      for (int ni = 0; ni < 4; ++ni)
        acc[mi][ni] = __builtin_amdgcn_mfma_f32_16x16x32_bf16(
            af[mi], bfr[ni], acc[mi][ni], 0, 0, 0);
    __builtin_amdgcn_s_setprio(0);
    int hi = t + 3; if (hi > nk - 1) hi = nk - 1;
    cbar(hi - (t + 1));
  }

  // --- LDS epilogue: two halves of 64 rows; full-line vectorized stores ---
#pragma unroll
  for (int half = 0; half < 2; ++half) {
    __syncthreads();
    if ((wave >> 1) == half) {
#pragma unroll
      for (int mi = 0; mi < 4; ++mi)
#pragma unroll
        for (int ni = 0; ni < 4; ++ni)
#pragma unroll
          for (int r = 0; r < 4; ++r)
            lC[(mi * 16 + quad * 4 + r) * 128 + wn + ni * 16 + l16] =
                acc[mi][ni][r] * alpha;
    }
    __syncthreads();
#pragma unroll
    for (int i = 0; i < 8; ++i) {
      int f = i * 256 + tid;             // 0..2047
      int row = f >> 5, cc = (f & 31) * 4;
      int m = row0 + half * 64 + row, n = col0 + cc;
      f32x4 v = *(const f32x4*)&lC[row * 128 + cc];
      long long ci = (long long)m * ldc + n;
      if (bias) {
        v[0] += b2f(bias[n]);     v[1] += b2f(bias[n + 1]);
        v[2] += b2f(bias[n + 2]); v[3] += b2f(bias[n + 3]);
      }
      if (resid) v += *(const f32x4*)&resid[ci];
      if (outf) *(f32x4*)&outf[ci] = v;
      if (outb) {
        bf16 c0 = f2b(v[0]), c1 = f2b(v[1]), c2 = f2b(v[2]), c3 = f2b(v[3]);
        ushort4 o = { *(unsigned short*)&c0, *(unsigned short*)&c1,
                      *(unsigned short*)&c2, *(unsigned short*)&c3 };
        *(ushort4*)&outb[ci] = o;
      }
    }
  }
}

// ---------------------------------------------------------------------------
// 256^2-tile GEMM (8 waves), BK=32, quad-buffer, depth-3, counted vmcnt.
// ---------------------------------------------------------------------------
__global__ __launch_bounds__(512, 2) void gemm256(
    const bf16* __restrict__ A, int lda,
    const bf16* __restrict__ Bt, int ldb,
    const bf16* __restrict__ bias,
    bf16* __restrict__ outb,
    int ldc, int K)
{
  __shared__ char smem[131072] __attribute__((aligned(16)));
  float* lC = (float*)smem;

  int tid = threadIdx.x;
  int lane = tid & 63;
  int wave = tid >> 6;
  int quad = lane >> 4, l16 = lane & 15;
  int wr = wave >> 2, wc = wave & 3;
  int wm = wr * 128, wn = wc * 64;
  int row0 = blockIdx.y * 256, col0 = blockIdx.x * 256;

  // staging source coords (inverse of frag_ld map), HALF=128, 2 rounds
  const bf16* asrc[2]; const bf16* bsrc[2];
#pragma unroll
  for (int i = 0; i < 2; ++i) {
    int line = i * 64 + (tid >> 3);
    int hx = (tid & 7) ^ (line & 7);
    int r = line + ((hx >> 2) << 7);
    int ke = (hx & 3) << 3;
    asrc[i] = A + (long long)(row0 + r) * lda + ke;
    bsrc[i] = Bt + (long long)(col0 + r) * ldb + ke;
  }

  auto stage = [&](int b, int t) {
    int o = t * 32;
#pragma unroll
    for (int i = 0; i < 2; ++i) {
      __builtin_amdgcn_global_load_lds((gbl_void*)(asrc[i] + o),
          (lds_void*)(smem + b * 16384 + i * 8192 + wave * 1024), 16, 0, 0);
      __builtin_amdgcn_global_load_lds((gbl_void*)(bsrc[i] + o),
          (lds_void*)(smem + 65536 + b * 16384 + i * 8192 + wave * 1024), 16, 0, 0);
    }
  };

  f32x4 acc[8][4];
#pragma unroll
  for (int a = 0; a < 8; ++a)
#pragma unroll
    for (int b = 0; b < 4; ++b) acc[a][b] = (f32x4){0.f, 0.f, 0.f, 0.f};

  int nk = K >> 5;
  stage(0, 0); stage(1, 1); stage(2, 2);
  cbar(2);

  for (int t = 0; t < nk; ++t) {
    if (t + 3 < nk) stage((t + 3) & 3, t + 3);
    const __bf16* lA = (const __bf16*)(smem + (t & 3) * 16384);
    const __bf16* lB = (const __bf16*)(smem + 65536 + (t & 3) * 16384);
    bf16x8 af[8], bfr[4];
#pragma unroll
    for (int mi = 0; mi < 8; ++mi) af[mi] = frag_ld<128>(lA, wm + mi * 16 + l16, quad);
#pragma unroll
    for (int ni = 0; ni < 4; ++ni) bfr[ni] = frag_ld<128>(lB, wn + ni * 16 + l16, quad);
    __builtin_amdgcn_s_setprio(1);
#pragma unroll
    for (int mi = 0; mi < 8; ++mi)
#pragma unroll
      for (int ni = 0; ni < 4; ++ni)
        acc[mi][ni] = __builtin_amdgcn_mfma_f32_16x16x32_bf16(
            af[mi], bfr[ni], acc[mi][ni], 0, 0, 0);
    __builtin_amdgcn_s_setprio(0);
    int hi = t + 3; if (hi > nk - 1) hi = nk - 1;
    cbar(hi - (t + 1));
  }

  // --- epilogue: 2 halves of 128 rows via fp32 LDS restage ---
#pragma unroll
  for (int h = 0; h < 2; ++h) {
    __syncthreads();
    if (wr == h) {
#pragma unroll
      for (int mi = 0; mi < 8; ++mi)
#pragma unroll
        for (int ni = 0; ni < 4; ++ni)
#pragma unroll
          for (int r = 0; r < 4; ++r)
            lC[(mi * 16 + quad * 4 + r) * 256 + wn + ni * 16 + l16] =
                acc[mi][ni][r];
    }
    __syncthreads();
#pragma unroll
    for (int it = 0; it < 16; ++it) {
      int f = it * 512 + tid;
      int row = f >> 6, cc = (f & 63) * 4;
      int m = row0 + h * 128 + row, n = col0 + cc;
      f32x4 v = *(const f32x4*)&lC[row * 256 + cc];
      v[0] += b2f(bias[n]);     v[1] += b2f(bias[n + 1]);
      v[2] += b2f(bias[n + 2]); v[3] += b2f(bias[n + 3]);
      bf16 c0 = f2b(v[0]), c1 = f2b(v[1]), c2 = f2b(v[2]), c3 = f2b(v[3]);
      ushort4 o = { *(unsigned short*)&c0, *(unsigned short*)&c1,
                    *(unsigned short*)&c2, *(unsigned short*)&c3 };
      *(ushort4*)&outb[(long long)m * ldc + n] = o;
    }
  }
}

// ---------------------------------------------------------------------------
// Split-K GEMM: pbuf[z][m][n] = A(K-chunk z) @ Bt^T. Same BK=32 pipeline.
// ---------------------------------------------------------------------------
__global__ __launch_bounds__(256, 2) void gemm_splitk(
    const bf16* __restrict__ A, int lda,
    const bf16* __restrict__ Bt, int ldb,
    float* __restrict__ pbuf, int ldc, int M, int KC)
{
  __shared__ char smem[65536] __attribute__((aligned(16)));

  int koff = blockIdx.z * KC;
  float* outz = pbuf + (long long)blockIdx.z * M * ldc;
  int tid = threadIdx.x;
  int lane = tid & 63;
  int wave = tid >> 6;
  int quad = lane >> 4, l16 = lane & 15;
  int wm = (wave >> 1) * 64, wn = (wave & 1) * 64;
  int row0 = blockIdx.y * 128, col0 = blockIdx.x * 128;

  const bf16* asrc[2]; const bf16* bsrc[2];
#pragma unroll
  for (int i = 0; i < 2; ++i) {
    int line = i * 32 + (tid >> 3);
    int hx = (tid & 7) ^ (line & 7);
    int r = line + ((hx >> 2) << 6);
    int ke = (hx & 3) << 3;
    asrc[i] = A + (long long)(row0 + r) * lda + koff + ke;
    bsrc[i] = Bt + (long long)(col0 + r) * ldb + koff + ke;
  }

  auto stage = [&](int b, int t) {
    int o = t * 32;
#pragma unroll
    for (int i = 0; i < 2; ++i) {
      __builtin_amdgcn_global_load_lds((gbl_void*)(asrc[i] + o),
          (lds_void*)(smem + b * 8192 + i * 4096 + wave * 1024), 16, 0, 0);
      __builtin_amdgcn_global_load_lds((gbl_void*)(bsrc[i] + o),
          (lds_void*)(smem + 32768 + b * 8192 + i * 4096 + wave * 1024), 16, 0, 0);
    }
  };

  f32x4 acc[4][4];
#pragma unroll
  for (int a = 0; a < 4; ++a)
#pragma unroll
    for (int b = 0; b < 4; ++b) acc[a][b] = (f32x4){0.f, 0.f, 0.f, 0.f};

  int nk = KC >> 5;                     // 8
  stage(0, 0); stage(1, 1); stage(2, 2);
  cbar(2);

  for (int t = 0; t < nk; ++t) {
    if (t + 3 < nk) stage((t + 3) & 3, t + 3);
    const __bf16* lA = (const __bf16*)(smem + (t & 3) * 8192);
    const __bf16* lB = (const __bf16*)(smem + 32768 + (t & 3) * 8192);
    bf16x8 af[4], bfr[4];
#pragma unroll
    for (int mi = 0; mi < 4; ++mi) af[mi] = frag_ld<64>(lA, wm + mi * 16 + l16, quad);
#pragma unroll
    for (int ni = 0; ni < 4; ++ni) bfr[ni] = frag_ld<64>(lB, wn + ni * 16 + l16, quad);
    __builtin_amdgcn_s_setprio(1);
#pragma unroll
    for (int mi = 0; mi < 4; ++mi)
#pragma unroll
      for (int ni = 0; ni < 4; ++ni)
        acc[mi][ni] = __builtin_amdgcn_mfma_f32_16x16x32_bf16(
            af[mi], bfr[ni], acc[mi][ni], 0, 0, 0);
    __builtin_amdgcn_s_setprio(0);
    int hi = t + 3; if (hi > nk - 1) hi = nk - 1;
    cbar(hi - (t + 1));
  }

#pragma unroll
  for (int mi = 0; mi < 4; ++mi)
#pragma unroll
    for (int ni = 0; ni < 4; ++ni) {
      int n = col0 + wn + ni * 16 + l16;
#pragma unroll
      for (int r = 0; r < 4; ++r) {
        int m = row0 + wm + mi * 16 + quad * 4 + r;
        outz[(long long)m * ldc + n] = acc[mi][ni][r];
      }
    }
}

// reduce 4 split-K partials + b2 + residual -> xf (fp32) and xbf (bf16)
__global__ void reduce_ff2(const float* __restrict__ pbuf, const bf16* __restrict__ bias,
                           float* __restrict__ xf, bf16* __restrict__ xbf) {
  int i = blockIdx.x * 256 + threadIdx.x;   // [0, 2048*1024)
  const int NT = 2048 * 1024;
  float v = xf[i] + b2f(bias[i & 1023]) +
            pbuf[i] + pbuf[i + NT] + pbuf[i + 2 * NT] + pbuf[i + 3 * NT];
  xf[i] = v;
  xbf[i] = f2b(v);
}

// ---------------------------------------------------------------------------
// Fused flash attention (unchanged from round 3)
// ---------------------------------------------------------------------------
__device__ __forceinline__ void fa_stage(
    const bf16* __restrict__ kb, const bf16* __restrict__ vtb, int j0, int tk,
    char* smem, int kboff, int vboff, int tid, int wave)
{
  int rounds = tk >> 6;
  for (int i = 0; i < rounds; ++i) {
    int rowk = i * 64 + (tid >> 3);
    int cbk = ((tid & 7) * 16) ^ ((rowk & 7) << 4);
    __builtin_amdgcn_global_load_lds(
        (gbl_void*)(kb + (long long)(j0 + rowk) * 1024 + (cbk >> 1)),
        (lds_void*)(smem + kboff + i * 8192 + wave * 1024), 16, 0, 0);
    int rowv, cbv;
    if (tk == 128) { rowv = i * 32 + (tid >> 4); cbv = ((tid & 15) * 16) ^ ((rowv & 7) << 4); }
    else           { rowv = (tid >> 3);          cbv = ((tid & 7) * 16) ^ ((rowv & 7) << 4); }
    __builtin_amdgcn_global_load_lds(
        (gbl_void*)(vtb + (long long)rowv * 8704 + j0 + (cbv >> 1)),
        (lds_void*)(smem + vboff + i * 8192 + wave * 1024), 16, 0, 0);
  }
}

template<int TK>
__device__ __forceinline__ void fa_compute(
    const char* smem, int kboff, int vboff,
    const bf16x8 (&qa)[2], bf16* lPw,
    int quad, int l16,
    f32x4 (&accO)[4], f32x4& mrow, f32x4& lrow)
{
  constexpr int NT = TK / 16;
  constexpr int NCH = TK / 32;
  const __bf16* lK = (const __bf16*)(smem + kboff);
  const __bf16* lV = (const __bf16*)(smem + vboff);
  int xork = (l16 & 7) << 3;

  f32x4 accS[NT];
#pragma unroll
  for (int ni = 0; ni < NT; ++ni) accS[ni] = (f32x4){0.f, 0.f, 0.f, 0.f};

#pragma unroll
  for (int ni = 0; ni < NT; ++ni)
#pragma unroll
    for (int ks = 0; ks < 2; ++ks) {
      bf16x8 bfr = *(const bf16x8*)&lK[(ni * 16 + l16) * 64 + ((ks * 32 + quad * 8) ^ xork)];
      accS[ni] = __builtin_amdgcn_mfma_f32_16x16x32_bf16(qa[ks], bfr, accS[ni], 0, 0, 0);
    }

  f32x4 vmax = (f32x4){-INFINITY, -INFINITY, -INFINITY, -INFINITY};
#pragma unroll
  for (int ni = 0; ni < NT; ++ni) {
    accS[ni] *= 0.125f;
    vmax = max4(vmax, accS[ni]);
  }
#pragma unroll
  for (int m = 1; m <= 8; m <<= 1) vmax = max4(vmax, shfl_xor4(vmax, m));
  f32x4 mnew = max4(mrow, vmax);
  f32x4 alpha = exp4(mrow - mnew);
  f32x4 rs = (f32x4){0.f, 0.f, 0.f, 0.f};
#pragma unroll
  for (int ni = 0; ni < NT; ++ni) {
    accS[ni] = exp4(accS[ni] - mnew);
    rs += accS[ni];
  }
#pragma unroll
  for (int m = 1; m <= 8; m <<= 1) rs += shfl_xor4(rs, m);
  lrow = lrow * alpha + rs;
  mrow = mnew;
#pragma unroll
  for (int nd = 0; nd < 4; ++nd) accO[nd] *= alpha;

#pragma unroll
  for (int c = 0; c < NCH; ++c) {
#pragma unroll
    for (int u = 0; u < 2; ++u)
#pragma unroll
      for (int r = 0; r < 4; ++r)
        lPw[(quad * 4 + r) * 40 + u * 16 + l16] = f2b(accS[c * 2 + u][r]);
    bf16x8 pa = *(const bf16x8*)&lPw[l16 * 40 + quad * 8];
#pragma unroll
    for (int nd = 0; nd < 4; ++nd) {
      bf16x8 vb = *(const bf16x8*)&lV[(nd * 16 + l16) * TK + ((c * 32 + quad * 8) ^ xork)];
      accO[nd] = __builtin_amdgcn_mfma_f32_16x16x32_bf16(pa, vb, accO[nd], 0, 0, 0);
    }
  }
}

__global__ __launch_bounds__(512, 2) void flash_attn(
    const bf16* __restrict__ q, const bf16* __restrict__ k,
    const bf16* __restrict__ vt, bf16* __restrict__ att)
{
  __shared__ char smem[75776] __attribute__((aligned(16)));

  int idx = blockIdx.x;
  int b = idx >> 5, h = (idx >> 1) & 15, half = idx & 1;
  int tid = threadIdx.x, wave = tid >> 6, lane = tid & 63;
  int quad = lane >> 4, l16 = lane & 15;
  int qrow0 = b * 256 + half * 128 + wave * 16;

  const bf16* kb  = k  + (long long)b * 1088 * 1024 + h * 64;
  const bf16* vtb = vt + (long long)(h * 64) * 8704 + b * 1088;
  bf16* lPw = (bf16*)(smem + 65536 + wave * 1280);

  bf16x8 qa[2];
#pragma unroll
  for (int ks = 0; ks < 2; ++ks)
    qa[ks] = *(const bf16x8*)&q[(long long)(qrow0 + l16) * 1024 +
                                h * 64 + ks * 32 + quad * 8];

  f32x4 accO[4];
  f32x4 mrow = (f32x4){-INFINITY, -INFINITY, -INFINITY, -INFINITY};
  f32x4 lrow = (f32x4){0.f, 0.f, 0.f, 0.f};
#pragma unroll
  for (int nd = 0; nd < 4; ++nd) accO[nd] = (f32x4){0.f, 0.f, 0.f, 0.f};

  fa_stage(kb, vtb, 0, 128, smem, 0, 32768, tid, wave);
  __syncthreads();

  for (int jt = 0; jt < 8; ++jt) {
    int buf = (jt & 1) * 16384;
    int nbuf = 16384 - buf;
    if (jt < 7) fa_stage(kb, vtb, (jt + 1) * 128, 128, smem, nbuf, 32768 + nbuf, tid, wave);
    else        fa_stage(kb, vtb, 1024, 64, smem, nbuf, 32768 + nbuf, tid, wave);
    fa_compute<128>(smem, buf, 32768 + buf, qa, lPw, quad, l16, accO, mrow, lrow);
    __syncthreads();
  }
  fa_compute<64>(smem, 0, 32768, qa, lPw, quad, l16, accO, mrow, lrow);

  f32x4 inv;
  inv[0] = 1.f / lrow[0]; inv[1] = 1.f / lrow[1];
  inv[2] = 1.f / lrow[2]; inv[3] = 1.f / lrow[3];
#pragma unroll
  for (int nd = 0; nd < 4; ++nd) {
    f32x4 o = accO[nd] * inv;
#pragma unroll
    for (int r = 0; r < 4; ++r)
      att[(long long)(qrow0 + quad * 4 + r) * 1024 +
          h * 64 + nd * 16 + l16] = f2b(o[r]);
  }
}

// ---------------------------------------------------------------------------
// Elementwise / helper kernels
// ---------------------------------------------------------------------------
__global__ void init_x_kernel(const void* __restrict__ x, const int* __restrict__ flag,
                              float* __restrict__ xf, bf16* __restrict__ xbf) {
  int i = blockIdx.x * 256 + threadIdx.x;
  float v = (*flag) ? b2f(((const bf16*)x)[i]) : ((const float*)x)[i];
  xf[i] = v;
  xbf[i] = f2b(v);
}

__global__ void transpose_w(const void* __restrict__ in, bf16* __restrict__ out,
                            int R, int C, const int* __restrict__ flag) {
  __shared__ bf16 tile[32][33];
  long long zoff = (long long)blockIdx.z * R * C;
  const bf16* inb = (const bf16*)in + zoff;
  const float* inf = (const float*)in + zoff;
  out += zoff;
  int tx = threadIdx.x, ty = threadIdx.y;
  int c0 = blockIdx.x * 32, r0 = blockIdx.y * 32;
  int isb = *flag;
#pragma unroll
  for (int i = 0; i < 4; ++i) {
    long long off = (long long)(r0 + ty + i * 8) * C + (c0 + tx);
    tile[ty + i * 8][tx] = isb ? inb[off] : f2b(inf[off]);
  }
  __syncthreads();
#pragma unroll
  for (int i = 0; i < 4; ++i)
    out[(long long)(c0 + ty + i * 8) * R + (r0 + tx)] = tile[tx][ty + i * 8];
}

__global__ void rotary_q_kernel(bf16* __restrict__ q, const bf16* __restrict__ srcf) {
  int idx = blockIdx.x * 256 + threadIdx.x;
  int row = idx >> 9;
  int p = idx & 511;
  int h = p >> 5, i = p & 31;
  int d0 = h * 64 + 2 * i;
  int ntok = row & 255;
  float f = b2f(srcf[ntok * 64 + 2 * i]);
  float c = cosf(f), s = sinf(f);
  long long base = (long long)row * 1024 + d0;
  float q0 = b2f(q[base]), q1 = b2f(q[base + 1]);
  q[base]     = f2b(q0 * c - q1 * s);
  q[base + 1] = f2b(q1 * c + q0 * s);
}

__global__ void k_bias_rot_kernel(bf16* __restrict__ k, const bf16* __restrict__ tgtf,
                                  const bf16* __restrict__ rpe,
                                  const int* __restrict__ ridx, int layer) {
  int idx = blockIdx.x * 256 + threadIdx.x;
  int b = idx >> 19;
  int rem = idx & ((1 << 19) - 1);
  int j = rem >> 9;
  int p = rem & 511;
  int h = p >> 5, i = p & 31;
  int d0 = h * 64 + 2 * i;
  float bias = b2f(rpe[(layer * 405 + ridx[j >> 8]) * 16 + h]);
  float f = b2f(tgtf[j * 64 + 2 * i]);
  float c = cosf(f), s = sinf(f);
  long long base = (long long)(b * 1088 + j) * 1024 + d0;
  float k0 = b2f(k[base]) + bias, k1 = b2f(k[base + 1]) + bias;
  k[base]     = f2b(k0 * c - k1 * s);
  k[base + 1] = f2b(k1 * c + k0 * s);
}

__global__ void geglu_kernel(const bf16* __restrict__ hgl, bf16* __restrict__ y) {
  int idx = blockIdx.x * 256 + threadIdx.x;
  int m = idx >> 12, n = idx & 4095;
  float a = b2f(hgl[(long long)m * 8192 + n]);
  float g = b2f(hgl[(long long)m * 8192 + 4096 + n]);
  float ge = 0.5f * g * (1.0f + erff(g * 0.70710678118654752f));
  y[idx] = f2b(a * ge);
}

// ---------------------------------------------------------------------------
extern "C" void kernel_launch(void* const* d_in, const int* in_sizes, int n_in,
                              void* d_out, int out_size, void* d_ws, size_t ws_size,
                              hipStream_t stream) {
  (void)in_sizes; (void)n_in; (void)out_size; (void)ws_size;
  const void* x    = d_in[0];
  const void* cond = d_in[1];
  const void* Wq   = d_in[2];
  const void* Wk   = d_in[3];
  const void* Wv   = d_in[4];
  const void* Wo   = d_in[5];
  const void* bo   = d_in[6];
  const void* rpe  = d_in[7];
  const void* W1   = d_in[8];
  const void* b1   = d_in[9];
  const void* W2   = d_in[10];
  const void* b2   = d_in[11];
  const void* srcf = d_in[12];
  const void* tgtf = d_in[13];
  const int*  ridx = (const int*)d_in[14];

  char* w = (char*)d_ws;
  int* flag = (int*)w;   w += 256;
  bf16* WqT = (bf16*)w;  w += (size_t)2 * 1024 * 1024 * 2;
  bf16* WkT = (bf16*)w;  w += (size_t)2 * 1024 * 1024 * 2;
  bf16* WvT = (bf16*)w;  w += (size_t)2 * 1024 * 1024 * 2;
  bf16* WoT = (bf16*)w;  w += (size_t)2 * 1024 * 1024 * 2;
  bf16* W1T = (bf16*)w;  w += (size_t)2 * 8192 * 1024 * 2;
  bf16* W2T = (bf16*)w;  w += (size_t)2 * 4096 * 1024 * 2;
  bf16* condb = (bf16*)w; w += (size_t)8704 * 1024 * 2;
  bf16* bo_b = (bf16*)w;  w += 2048 * 2;
  bf16* rpe_b = (bf16*)w; w += 12960 * 2;
  bf16* b1_b = (bf16*)w;  w += 16384 * 2;
  bf16* b2_b = (bf16*)w;  w += 2048 * 2;
  bf16* srcf_b = (bf16*)w; w += 16384 * 2;
  bf16* tgtf_b = (bf16*)w; w += 65536 * 2;
  float* xf = (float*)w; w += (size_t)2048 * 1024 * 4;
  bf16* xbf = (bf16*)w;  w += (size_t)2048 * 1024 * 2;
  bf16* qbuf = (bf16*)w; w += (size_t)2048 * 1024 * 2;
  bf16* kbuf = (bf16*)w; w += (size_t)8704 * 1024 * 2;
  bf16* vTf = (bf16*)w;  w += (size_t)1024 * 8704 * 2;
  bf16* att = (bf16*)w;  w += (size_t)2048 * 1024 * 2;
  bf16* hgl = (bf16*)w;  w += (size_t)2048 * 8192 * 2;   // 32 MiB
  bf16* ybuf = (bf16*)w; w += (size_t)2048 * 4096 * 2;   // 16 MiB
  float* pbuf = (float*)hgl;  // split-K partials (4 x 8 MiB) alias dead hgl

  detect_dtype<<<1, 1, 0, stream>>>((const unsigned int*)x, flag);

  convert_in<<<34816, 256, 0, stream>>>(cond, condb, 8704 * 1024, flag);
  convert_in<<<8, 256, 0, stream>>>(bo, bo_b, 2048, flag);
  convert_in<<<51, 256, 0, stream>>>(rpe, rpe_b, 12960, flag);
  convert_in<<<64, 256, 0, stream>>>(b1, b1_b, 16384, flag);
  convert_in<<<8, 256, 0, stream>>>(b2, b2_b, 2048, flag);
  convert_in<<<64, 256, 0, stream>>>(srcf, srcf_b, 16384, flag);
  convert_in<<<256, 256, 0, stream>>>(tgtf, tgtf_b, 65536, flag);

  dim3 tb(32, 8);
  transpose_w<<<dim3(32, 32, 2),  tb, 0, stream>>>(Wq, WqT, 1024, 1024, flag);
  transpose_w<<<dim3(32, 32, 2),  tb, 0, stream>>>(Wk, WkT, 1024, 1024, flag);
  transpose_w<<<dim3(32, 32, 2),  tb, 0, stream>>>(Wv, WvT, 1024, 1024, flag);
  transpose_w<<<dim3(32, 32, 2),  tb, 0, stream>>>(Wo, WoT, 1024, 1024, flag);
  transpose_w<<<dim3(256, 32, 2), tb, 0, stream>>>(W1, W1T, 1024, 8192, flag);
  transpose_w<<<dim3(32, 128, 2), tb, 0, stream>>>(W2, W2T, 4096, 1024, flag);
  init_x_kernel<<<8192, 256, 0, stream>>>(x, flag, xf, xbf);

  for (int l = 0; l < 2; ++l) {
    const bf16* WqTl = WqT + (size_t)l * 1024 * 1024;
    const bf16* WkTl = WkT + (size_t)l * 1024 * 1024;
    const bf16* WvTl = WvT + (size_t)l * 1024 * 1024;
    const bf16* WoTl = WoT + (size_t)l * 1024 * 1024;
    const bf16* W1Tl = W1T + (size_t)l * 8192 * 1024;
    const bf16* W2Tl = W2T + (size_t)l * 4096 * 1024;

    // TAG 0: q = x @ Wq   (M=2048, N=1024)
    gemm_bt<0><<<dim3(8, 16), 256, 0, stream>>>(xbf, 1024, WqTl, 1024, 1.f,
        nullptr, nullptr, nullptr, qbuf, 1024, 1024);
    rotary_q_kernel<<<4096, 256, 0, stream>>>(qbuf, srcf_b);
    // TAG 1: V^T = Wv^T @ cond^T   (M=1024, N=8704)
    gemm_bt<1><<<dim3(68, 8), 256, 0, stream>>>(WvTl, 1024, condb, 1024, 1.f,
        nullptr, nullptr, nullptr, vTf, 8704, 1024);
    // TAG 2: k = cond @ Wk   (M=8704, N=1024)
    gemm_bt<2><<<dim3(8, 68), 256, 0, stream>>>(condb, 1024, WkTl, 1024, 1.f,
        nullptr, nullptr, nullptr, kbuf, 1024, 1024);
    k_bias_rot_kernel<<<16384, 256, 0, stream>>>(kbuf, tgtf_b, rpe_b, ridx, l);
    // fused attention (8 waves x 16 q-rows, dbuf prefetch)
    flash_attn<<<256, 512, 0, stream>>>(qbuf, kbuf, vTf, att);
    // TAG 3: x = x + O @ Wo + bo   (M=2048, N=1024)
    gemm_bt<3><<<dim3(8, 16), 256, 0, stream>>>(att, 1024, WoTl, 1024, 1.f,
        xf, bo_b + (size_t)l * 1024, xf, xbf, 1024, 1024);
    // FF1 hgl = x @ W1 + b1   (M=2048, N=8192) -- 256^2 tile kernel
    gemm256<<<dim3(32, 8), 512, 0, stream>>>(xbf, 1024, W1Tl, 1024,
        b1_b + (size_t)l * 8192, hgl, 8192, 1024);
    geglu_kernel<<<32768, 256, 0, stream>>>(hgl, ybuf);
    // FF2 split-K into partials (alias hgl, now dead) + fused reduce
    gemm_splitk<<<dim3(8, 16, 4), 256, 0, stream>>>(ybuf, 4096, W2Tl, 4096,
                                                    pbuf, 1024, 2048, 1024);
    reduce_ff2<<<8192, 256, 0, stream>>>(pbuf, b2_b + (size_t)l * 1024, xf, xbf);
  }

  emit_kernel<<<8192, 256, 0, stream>>>(xf, flag, d_out);
}

// Round 5
// 743.026 us; speedup vs baseline: 2.4928x; 1.0550x over previous
//
#include <hip/hip_runtime.h>
#include <hip/hip_bf16.h>
#include <math.h>

typedef __hip_bfloat16 bf16;
typedef __bf16 bf16x8 __attribute__((ext_vector_type(8)));
typedef float f32x4 __attribute__((ext_vector_type(4)));

typedef __attribute__((address_space(3))) void lds_void;
typedef const __attribute__((address_space(1))) void gbl_void;

__device__ __forceinline__ float b2f(bf16 v) { return __bfloat162float(v); }
__device__ __forceinline__ bf16 f2b(float v) { return __float2bfloat16(v); }

__device__ __forceinline__ f32x4 shfl_xor4(f32x4 v, int m) {
  f32x4 o;
  o[0] = __shfl_xor(v[0], m);
  o[1] = __shfl_xor(v[1], m);
  o[2] = __shfl_xor(v[2], m);
  o[3] = __shfl_xor(v[3], m);
  return o;
}
__device__ __forceinline__ f32x4 max4(f32x4 a, f32x4 b) {
  f32x4 o;
  o[0] = fmaxf(a[0], b[0]); o[1] = fmaxf(a[1], b[1]);
  o[2] = fmaxf(a[2], b[2]); o[3] = fmaxf(a[3], b[3]);
  return o;
}
__device__ __forceinline__ f32x4 exp4(f32x4 a) {
  f32x4 o;
  o[0] = __expf(a[0]); o[1] = __expf(a[1]);
  o[2] = __expf(a[2]); o[3] = __expf(a[3]);
  return o;
}

// counted-vmcnt barriers (T4): never drain to 0 mid-loop.
// quad-buffer depth-3 variant (each stage batch = 4 loads)
__device__ __forceinline__ void cbar(int ahead) {
  if (ahead >= 2)      asm volatile("s_waitcnt vmcnt(8)" ::: "memory");
  else if (ahead == 1) asm volatile("s_waitcnt vmcnt(4)" ::: "memory");
  else                 asm volatile("s_waitcnt vmcnt(0)" ::: "memory");
  __builtin_amdgcn_s_barrier();
  __builtin_amdgcn_sched_barrier(0);
}
// triple-buffer depth-2 variant
__device__ __forceinline__ void cbar2(int ahead) {
  if (ahead >= 1) asm volatile("s_waitcnt vmcnt(4)" ::: "memory");
  else            asm volatile("s_waitcnt vmcnt(0)" ::: "memory");
  __builtin_amdgcn_s_barrier();
  __builtin_amdgcn_sched_barrier(0);
}

// T1: bijective XCD chunk-swizzle of a flat block index (nwg blocks, 8 XCDs).
__device__ __forceinline__ int xcd_swz(int flat, int nwg) {
  int q = nwg >> 3, r = nwg & 7;
  int xcd = flat & 7, pos = flat >> 3;
  return (xcd < r) ? (xcd * (q + 1) + pos) : (r * (q + 1) + (xcd - r) * q + pos);
}

// ---------------------------------------------------------------------------
// dtype detection (inputs bf16 vs fp32), device-side, deterministic per call
// ---------------------------------------------------------------------------
__global__ void detect_dtype(const unsigned int* __restrict__ x, int* __restrict__ flag) {
  int cnt = 0;
  for (int i = 0; i < 128; ++i) {
    unsigned int lo = x[i] & 0xFFFFu;
    unsigned int e = (lo >> 7) & 0xFFu;
    if (e >= 100u && e <= 140u) ++cnt;
  }
  *flag = (cnt >= 96) ? 1 : 0;
}

__global__ void convert_in(const void* __restrict__ src, bf16* __restrict__ dst,
                           int n, const int* __restrict__ flag) {
  int i = blockIdx.x * 256 + threadIdx.x;
  if (i >= n) return;
  dst[i] = (*flag) ? ((const bf16*)src)[i] : f2b(((const float*)src)[i]);
}

__global__ void emit_kernel(const float* __restrict__ xf, const int* __restrict__ flag,
                            void* __restrict__ out) {
  int i = blockIdx.x * 256 + threadIdx.x;
  if (*flag) ((bf16*)out)[i] = f2b(xf[i]);
  else       ((float*)out)[i] = xf[i];
}

// ---------------------------------------------------------------------------
// LDS K-tile layout (BK=32): [2*HALF rows][32 k] bf16 packed as HALF lines
// x 128B; logical (r,kslot) at line (r&(HALF-1)), slot (((r>>LB)<<2)|k)^(line&7).
// ---------------------------------------------------------------------------
template<int HALF>
__device__ __forceinline__ bf16x8 frag_ld(const __bf16* lt, int r, int quad) {
  constexpr int LB = (HALF == 128) ? 7 : 6;
  int line = r & (HALF - 1);
  int sl = (((r >> LB) << 2) | quad) ^ (line & 7);
  return *(const bf16x8*)&lt[line * 64 + sl * 8];
}

// ---------------------------------------------------------------------------
// 128^2-tile GEMM, BK=32, TRIPLE-buffered LDS (48 KB -> 3 blocks/CU),
// prefetch depth 2, counted vmcnt, XCD chunk-swizzle (big-dim-major).
// ---------------------------------------------------------------------------
template<int TAG>
__global__ __launch_bounds__(256, 3) void gemm_bt(
    const bf16* __restrict__ A, int lda,
    const bf16* __restrict__ Bt, int ldb,
    float alpha,
    const float* __restrict__ resid,
    const bf16* __restrict__ bias,
    float* __restrict__ outf,
    bf16* __restrict__ outb,
    int ldc, int K)
{
  __shared__ char smem[49152] __attribute__((aligned(16)));
  float* lC = (float*)smem;            // epilogue alias (32 KB = 64x128 f32)

  int tid = threadIdx.x;
  int lane = tid & 63;
  int wave = tid >> 6;
  int quad = lane >> 4, l16 = lane & 15;
  int wm = (wave >> 1) * 64, wn = (wave & 1) * 64;

  // XCD swizzle: flatten with the LARGE grid dim outermost so each XCD chunk
  // covers all small-dim blocks (operand-panel reuse within one L2).
  int gx = gridDim.x, gy = gridDim.y;
  int nwg = gx * gy;
  bool ymaj = gy >= gx;
  int flat = ymaj ? ((int)blockIdx.y * gx + blockIdx.x)
                  : ((int)blockIdx.x * gy + blockIdx.y);
  int swz = xcd_swz(flat, nwg);
  int bx, by;
  if (ymaj) { by = swz / gx; bx = swz - by * gx; }
  else      { bx = swz / gy; by = swz - bx * gy; }
  int row0 = by * 128, col0 = bx * 128;

  const bf16* asrc[2]; const bf16* bsrc[2];
#pragma unroll
  for (int i = 0; i < 2; ++i) {
    int line = i * 32 + (tid >> 3);
    int hx = (tid & 7) ^ (line & 7);
    int r = line + ((hx >> 2) << 6);
    int ke = (hx & 3) << 3;
    asrc[i] = A + (long long)(row0 + r) * lda + ke;
    bsrc[i] = Bt + (long long)(col0 + r) * ldb + ke;
  }

  auto stage = [&](int b, int t) {
    int o = t * 32;
#pragma unroll
    for (int i = 0; i < 2; ++i) {
      __builtin_amdgcn_global_load_lds((gbl_void*)(asrc[i] + o),
          (lds_void*)(smem + b * 8192 + i * 4096 + wave * 1024), 16, 0, 0);
      __builtin_amdgcn_global_load_lds((gbl_void*)(bsrc[i] + o),
          (lds_void*)(smem + 24576 + b * 8192 + i * 4096 + wave * 1024), 16, 0, 0);
    }
  };

  f32x4 acc[4][4];
#pragma unroll
  for (int a = 0; a < 4; ++a)
#pragma unroll
    for (int b = 0; b < 4; ++b) acc[a][b] = (f32x4){0.f, 0.f, 0.f, 0.f};

  int nk = K >> 5;                      // BK=32 tiles
  stage(0, 0); stage(1, 1);
  cbar2(1);                             // drain batch 0, keep batch 1

  for (int t = 0; t < nk; ++t) {
    if (t + 2 < nk) stage((t + 2) % 3, t + 2);
    int bt = t % 3;
    const __bf16* lA = (const __bf16*)(smem + bt * 8192);
    const __bf16* lB = (const __bf16*)(smem + 24576 + bt * 8192);
    bf16x8 af[4], bfr[4];
#pragma unroll
    for (int mi = 0; mi < 4; ++mi) af[mi] = frag_ld<64>(lA, wm + mi * 16 + l16, quad);
#pragma unroll
    for (int ni = 0; ni < 4; ++ni) bfr[ni] = frag_ld<64>(lB, wn + ni * 16 + l16, quad);
    __builtin_amdgcn_s_setprio(1);
#pragma unroll
    for (int mi = 0; mi < 4; ++mi)
#pragma unroll
      for (int ni = 0; ni < 4; ++ni)
        acc[mi][ni] = __builtin_amdgcn_mfma_f32_16x16x32_bf16(
            af[mi], bfr[ni], acc[mi][ni], 0, 0, 0);
    __builtin_amdgcn_s_setprio(0);
    int ahead = nk - 1 - (t + 1); if (ahead > 1) ahead = 1;
    cbar2(ahead);
  }

  // --- LDS epilogue: two halves of 64 rows; full-line vectorized stores ---
#pragma unroll
  for (int half = 0; half < 2; ++half) {
    __syncthreads();
    if ((wave >> 1) == half) {
#pragma unroll
      for (int mi = 0; mi < 4; ++mi)
#pragma unroll
        for (int ni = 0; ni < 4; ++ni)
#pragma unroll
          for (int r = 0; r < 4; ++r)
            lC[(mi * 16 + quad * 4 + r) * 128 + wn + ni * 16 + l16] =
                acc[mi][ni][r] * alpha;
    }
    __syncthreads();
#pragma unroll
    for (int i = 0; i < 8; ++i) {
      int f = i * 256 + tid;             // 0..2047
      int row = f >> 5, cc = (f & 31) * 4;
      int m = row0 + half * 64 + row, n = col0 + cc;
      f32x4 v = *(const f32x4*)&lC[row * 128 + cc];
      long long ci = (long long)m * ldc + n;
      if (bias) {
        v[0] += b2f(bias[n]);     v[1] += b2f(bias[n + 1]);
        v[2] += b2f(bias[n + 2]); v[3] += b2f(bias[n + 3]);
      }
      if (resid) v += *(const f32x4*)&resid[ci];
      if (outf) *(f32x4*)&outf[ci] = v;
      if (outb) {
        bf16 c0 = f2b(v[0]), c1 = f2b(v[1]), c2 = f2b(v[2]), c3 = f2b(v[3]);
        ushort4 o = { *(unsigned short*)&c0, *(unsigned short*)&c1,
                      *(unsigned short*)&c2, *(unsigned short*)&c3 };
        *(ushort4*)&outb[ci] = o;
      }
    }
  }
}

// ---------------------------------------------------------------------------
// FF1 fused GEMM+GEGLU: 256-row x (128a + 128g)-col tile. B-staging pulls
// a-cols from W1T rows [c,c+128) and g-cols from rows [4096+c, ...). The
// epilogue computes y = (a+b1a) * gelu(g+b1g) and stores 128 bf16 cols.
// 8 waves, BK=32, quad-buffer depth 3, counted vmcnt.
// ---------------------------------------------------------------------------
__global__ __launch_bounds__(512, 2) void gemm256_geglu(
    const bf16* __restrict__ A, int lda,
    const bf16* __restrict__ W1t, int ldb,
    const bf16* __restrict__ bias,          // b1, length 8192
    bf16* __restrict__ outy, int ldy, int K)
{
  __shared__ char smem[131072] __attribute__((aligned(16)));
  float* lC = (float*)smem;

  int tid = threadIdx.x;
  int lane = tid & 63;
  int wave = tid >> 6;
  int quad = lane >> 4, l16 = lane & 15;
  int wr = wave >> 2, wc = wave & 3;
  int wm = wr * 128, wn = wc * 64;
  int row0 = blockIdx.y * 256, col0 = blockIdx.x * 128;   // 128 output cols

  const bf16* asrc[2]; const bf16* bsrc[2];
#pragma unroll
  for (int i = 0; i < 2; ++i) {
    int line = i * 64 + (tid >> 3);
    int hx = (tid & 7) ^ (line & 7);
    int rA = line + ((hx >> 2) << 7);
    int ke = (hx & 3) << 3;
    asrc[i] = A + (long long)(row0 + rA) * lda + ke;
    int rowW = (hx & 4) ? (4096 + col0 + line) : (col0 + line);
    bsrc[i] = W1t + (long long)rowW * ldb + ke;
  }

  auto stage = [&](int b, int t) {
    int o = t * 32;
#pragma unroll
    for (int i = 0; i < 2; ++i) {
      __builtin_amdgcn_global_load_lds((gbl_void*)(asrc[i] + o),
          (lds_void*)(smem + b * 16384 + i * 8192 + wave * 1024), 16, 0, 0);
      __builtin_amdgcn_global_load_lds((gbl_void*)(bsrc[i] + o),
          (lds_void*)(smem + 65536 + b * 16384 + i * 8192 + wave * 1024), 16, 0, 0);
    }
  };

  f32x4 acc[8][4];
#pragma unroll
  for (int a = 0; a < 8; ++a)
#pragma unroll
    for (int b = 0; b < 4; ++b) acc[a][b] = (f32x4){0.f, 0.f, 0.f, 0.f};

  int nk = K >> 5;
  stage(0, 0); stage(1, 1); stage(2, 2);
  cbar(2);

  for (int t = 0; t < nk; ++t) {
    if (t + 3 < nk) stage((t + 3) & 3, t + 3);
    const __bf16* lA = (const __bf16*)(smem + (t & 3) * 16384);
    const __bf16* lB = (const __bf16*)(smem + 65536 + (t & 3) * 16384);
    bf16x8 af[8], bfr[4];
#pragma unroll
    for (int mi = 0; mi < 8; ++mi) af[mi] = frag_ld<128>(lA, wm + mi * 16 + l16, quad);
#pragma unroll
    for (int ni = 0; ni < 4; ++ni) bfr[ni] = frag_ld<128>(lB, wn + ni * 16 + l16, quad);
    __builtin_amdgcn_s_setprio(1);
#pragma unroll
    for (int mi = 0; mi < 8; ++mi)
#pragma unroll
      for (int ni = 0; ni < 4; ++ni)
        acc[mi][ni] = __builtin_amdgcn_mfma_f32_16x16x32_bf16(
            af[mi], bfr[ni], acc[mi][ni], 0, 0, 0);
    __builtin_amdgcn_s_setprio(0);
    int hi = t + 3; if (hi > nk - 1) hi = nk - 1;
    cbar(hi - (t + 1));
  }

  // --- epilogue: restage fp32 [128 rows][256 logical cols], fuse GEGLU ---
#pragma unroll
  for (int h = 0; h < 2; ++h) {
    __syncthreads();
    if (wr == h) {
#pragma unroll
      for (int mi = 0; mi < 8; ++mi)
#pragma unroll
        for (int ni = 0; ni < 4; ++ni)
#pragma unroll
          for (int r = 0; r < 4; ++r)
            lC[(mi * 16 + quad * 4 + r) * 256 + wn + ni * 16 + l16] =
                acc[mi][ni][r];
    }
    __syncthreads();
#pragma unroll
    for (int it = 0; it < 8; ++it) {
      int f = it * 512 + tid;            // 0..4095
      int row = f >> 5, cc = (f & 31) * 4;
      int m = row0 + h * 128 + row, n = col0 + cc;
      f32x4 a = *(const f32x4*)&lC[row * 256 + cc];
      f32x4 g = *(const f32x4*)&lC[row * 256 + 128 + cc];
      bf16 yb[4];
#pragma unroll
      for (int j = 0; j < 4; ++j) {
        float av = a[j] + b2f(bias[n + j]);
        float gv = g[j] + b2f(bias[4096 + n + j]);
        float ge = 0.5f * gv * (1.0f + erff(gv * 0.70710678118654752f));
        yb[j] = f2b(av * ge);
      }
      ushort4 o = { *(unsigned short*)&yb[0], *(unsigned short*)&yb[1],
                    *(unsigned short*)&yb[2], *(unsigned short*)&yb[3] };
      *(ushort4*)&outy[(long long)m * ldy + n] = o;
    }
  }
}

// ---------------------------------------------------------------------------
// Split-K GEMM: pbuf[z][m][n] = A(K-chunk z) @ Bt^T.
// Triple-buffer (48 KB -> 3 blocks/CU), depth 2, XCD swizzle on (x,y).
// ---------------------------------------------------------------------------
__global__ __launch_bounds__(256, 3) void gemm_splitk(
    const bf16* __restrict__ A, int lda,
    const bf16* __restrict__ Bt, int ldb,
    float* __restrict__ pbuf, int ldc, int M, int KC)
{
  __shared__ char smem[49152] __attribute__((aligned(16)));

  int koff = blockIdx.z * KC;
  float* outz = pbuf + (long long)blockIdx.z * M * ldc;
  int tid = threadIdx.x;
  int lane = tid & 63;
  int wave = tid >> 6;
  int quad = lane >> 4, l16 = lane & 15;
  int wm = (wave >> 1) * 64, wn = (wave & 1) * 64;

  int gx = gridDim.x, gy = gridDim.y;
  int nwg = gx * gy;
  bool ymaj = gy >= gx;
  int flat = ymaj ? ((int)blockIdx.y * gx + blockIdx.x)
                  : ((int)blockIdx.x * gy + blockIdx.y);
  int swz = xcd_swz(flat, nwg);
  int bx, by;
  if (ymaj) { by = swz / gx; bx = swz - by * gx; }
  else      { bx = swz / gy; by = swz - bx * gy; }
  int row0 = by * 128, col0 = bx * 128;

  const bf16* asrc[2]; const bf16* bsrc[2];
#pragma unroll
  for (int i = 0; i < 2; ++i) {
    int line = i * 32 + (tid >> 3);
    int hx = (tid & 7) ^ (line & 7);
    int r = line + ((hx >> 2) << 6);
    int ke = (hx & 3) << 3;
    asrc[i] = A + (long long)(row0 + r) * lda + koff + ke;
    bsrc[i] = Bt + (long long)(col0 + r) * ldb + koff + ke;
  }

  auto stage = [&](int b, int t) {
    int o = t * 32;
#pragma unroll
    for (int i = 0; i < 2; ++i) {
      __builtin_amdgcn_global_load_lds((gbl_void*)(asrc[i] + o),
          (lds_void*)(smem + b * 8192 + i * 4096 + wave * 1024), 16, 0, 0);
      __builtin_amdgcn_global_load_lds((gbl_void*)(bsrc[i] + o),
          (lds_void*)(smem + 24576 + b * 8192 + i * 4096 + wave * 1024), 16, 0, 0);
    }
  };

  f32x4 acc[4][4];
#pragma unroll
  for (int a = 0; a < 4; ++a)
#pragma unroll
    for (int b = 0; b < 4; ++b) acc[a][b] = (f32x4){0.f, 0.f, 0.f, 0.f};

  int nk = KC >> 5;
  stage(0, 0); stage(1, 1);
  cbar2(1);

  for (int t = 0; t < nk; ++t) {
    if (t + 2 < nk) stage((t + 2) % 3, t + 2);
    int bt = t % 3;
    const __bf16* lA = (const __bf16*)(smem + bt * 8192);
    const __bf16* lB = (const __bf16*)(smem + 24576 + bt * 8192);
    bf16x8 af[4], bfr[4];
#pragma unroll
    for (int mi = 0; mi < 4; ++mi) af[mi] = frag_ld<64>(lA, wm + mi * 16 + l16, quad);
#pragma unroll
    for (int ni = 0; ni < 4; ++ni) bfr[ni] = frag_ld<64>(lB, wn + ni * 16 + l16, quad);
    __builtin_amdgcn_s_setprio(1);
#pragma unroll
    for (int mi = 0; mi < 4; ++mi)
#pragma unroll
      for (int ni = 0; ni < 4; ++ni)
        acc[mi][ni] = __builtin_amdgcn_mfma_f32_16x16x32_bf16(
            af[mi], bfr[ni], acc[mi][ni], 0, 0, 0);
    __builtin_amdgcn_s_setprio(0);
    int ahead = nk - 1 - (t + 1); if (ahead > 1) ahead = 1;
    cbar2(ahead);
  }

#pragma unroll
  for (int mi = 0; mi < 4; ++mi)
#pragma unroll
    for (int ni = 0; ni < 4; ++ni) {
      int n = col0 + wn + ni * 16 + l16;
#pragma unroll
      for (int r = 0; r < 4; ++r) {
        int m = row0 + wm + mi * 16 + quad * 4 + r;
        outz[(long long)m * ldc + n] = acc[mi][ni][r];
      }
    }
}

// reduce 4 split-K partials + b2 + residual -> xf (fp32) and xbf (bf16)
__global__ void reduce_ff2(const float* __restrict__ pbuf, const bf16* __restrict__ bias,
                           float* __restrict__ xf, bf16* __restrict__ xbf) {
  int i = blockIdx.x * 256 + threadIdx.x;   // [0, 2048*1024)
  const int NT = 2048 * 1024;
  float v = xf[i] + b2f(bias[i & 1023]) +
            pbuf[i] + pbuf[i + NT] + pbuf[i + 2 * NT] + pbuf[i + 3 * NT];
  xf[i] = v;
  xbf[i] = f2b(v);
}

// ---------------------------------------------------------------------------
// Fused flash attention (round-3 structure + XCD swizzle: one batch b/XCD)
// ---------------------------------------------------------------------------
__device__ __forceinline__ void fa_stage(
    const bf16* __restrict__ kb, const bf16* __restrict__ vtb, int j0, int tk,
    char* smem, int kboff, int vboff, int tid, int wave)
{
  int rounds = tk >> 6;
  for (int i = 0; i < rounds; ++i) {
    int rowk = i * 64 + (tid >> 3);
    int cbk = ((tid & 7) * 16) ^ ((rowk & 7) << 4);
    __builtin_amdgcn_global_load_lds(
        (gbl_void*)(kb + (long long)(j0 + rowk) * 1024 + (cbk >> 1)),
        (lds_void*)(smem + kboff + i * 8192 + wave * 1024), 16, 0, 0);
    int rowv, cbv;
    if (tk == 128) { rowv = i * 32 + (tid >> 4); cbv = ((tid & 15) * 16) ^ ((rowv & 7) << 4); }
    else           { rowv = (tid >> 3);          cbv = ((tid & 7) * 16) ^ ((rowv & 7) << 4); }
    __builtin_amdgcn_global_load_lds(
        (gbl_void*)(vtb + (long long)rowv * 8704 + j0 + (cbv >> 1)),
        (lds_void*)(smem + vboff + i * 8192 + wave * 1024), 16, 0, 0);
  }
}

template<int TK>
__device__ __forceinline__ void fa_compute(
    const char* smem, int kboff, int vboff,
    const bf16x8 (&qa)[2], bf16* lPw,
    int quad, int l16,
    f32x4 (&accO)[4], f32x4& mrow, f32x4& lrow)
{
  constexpr int NT = TK / 16;
  constexpr int NCH = TK / 32;
  const __bf16* lK = (const __bf16*)(smem + kboff);
  const __bf16* lV = (const __bf16*)(smem + vboff);
  int xork = (l16 & 7) << 3;

  f32x4 accS[NT];
#pragma unroll
  for (int ni = 0; ni < NT; ++ni) accS[ni] = (f32x4){0.f, 0.f, 0.f, 0.f};

#pragma unroll
  for (int ni = 0; ni < NT; ++ni)
#pragma unroll
    for (int ks = 0; ks < 2; ++ks) {
      bf16x8 bfr = *(const bf16x8*)&lK[(ni * 16 + l16) * 64 + ((ks * 32 + quad * 8) ^ xork)];
      accS[ni] = __builtin_amdgcn_mfma_f32_16x16x32_bf16(qa[ks], bfr, accS[ni], 0, 0, 0);
    }

  f32x4 vmax = (f32x4){-INFINITY, -INFINITY, -INFINITY, -INFINITY};
#pragma unroll
  for (int ni = 0; ni < NT; ++ni) {
    accS[ni] *= 0.125f;
    vmax = max4(vmax, accS[ni]);
  }
#pragma unroll
  for (int m = 1; m <= 8; m <<= 1) vmax = max4(vmax, shfl_xor4(vmax, m));
  f32x4 mnew = max4(mrow, vmax);
  f32x4 alpha = exp4(mrow - mnew);
  f32x4 rs = (f32x4){0.f, 0.f, 0.f, 0.f};
#pragma unroll
  for (int ni = 0; ni < NT; ++ni) {
    accS[ni] = exp4(accS[ni] - mnew);
    rs += accS[ni];
  }
#pragma unroll
  for (int m = 1; m <= 8; m <<= 1) rs += shfl_xor4(rs, m);
  lrow = lrow * alpha + rs;
  mrow = mnew;
#pragma unroll
  for (int nd = 0; nd < 4; ++nd) accO[nd] *= alpha;

#pragma unroll
  for (int c = 0; c < NCH; ++c) {
#pragma unroll
    for (int u = 0; u < 2; ++u)
#pragma unroll
      for (int r = 0; r < 4; ++r)
        lPw[(quad * 4 + r) * 40 + u * 16 + l16] = f2b(accS[c * 2 + u][r]);
    bf16x8 pa = *(const bf16x8*)&lPw[l16 * 40 + quad * 8];
#pragma unroll
    for (int nd = 0; nd < 4; ++nd) {
      bf16x8 vb = *(const bf16x8*)&lV[(nd * 16 + l16) * TK + ((c * 32 + quad * 8) ^ xork)];
      accO[nd] = __builtin_amdgcn_mfma_f32_16x16x32_bf16(pa, vb, accO[nd], 0, 0, 0);
    }
  }
}

__global__ __launch_bounds__(512, 2) void flash_attn(
    const bf16* __restrict__ q, const bf16* __restrict__ k,
    const bf16* __restrict__ vt, bf16* __restrict__ att)
{
  __shared__ char smem[75776] __attribute__((aligned(16)));

  int idx = xcd_swz(blockIdx.x, gridDim.x);   // chunk: one batch b per XCD
  int b = idx >> 5, h = (idx >> 1) & 15, half = idx & 1;
  int tid = threadIdx.x, wave = tid >> 6, lane = tid & 63;
  int quad = lane >> 4, l16 = lane & 15;
  int qrow0 = b * 256 + half * 128 + wave * 16;

  const bf16* kb  = k  + (long long)b * 1088 * 1024 + h * 64;
  const bf16* vtb = vt + (long long)(h * 64) * 8704 + b * 1088;
  bf16* lPw = (bf16*)(smem + 65536 + wave * 1280);

  bf16x8 qa[2];
#pragma unroll
  for (int ks = 0; ks < 2; ++ks)
    qa[ks] = *(const bf16x8*)&q[(long long)(qrow0 + l16) * 1024 +
                                h * 64 + ks * 32 + quad * 8];

  f32x4 accO[4];
  f32x4 mrow = (f32x4){-INFINITY, -INFINITY, -INFINITY, -INFINITY};
  f32x4 lrow = (f32x4){0.f, 0.f, 0.f, 0.f};
#pragma unroll
  for (int nd = 0; nd < 4; ++nd) accO[nd] = (f32x4){0.f, 0.f, 0.f, 0.f};

  fa_stage(kb, vtb, 0, 128, smem, 0, 32768, tid, wave);
  __syncthreads();

  for (int jt = 0; jt < 8; ++jt) {
    int buf = (jt & 1) * 16384;
    int nbuf = 16384 - buf;
    if (jt < 7) fa_stage(kb, vtb, (jt + 1) * 128, 128, smem, nbuf, 32768 + nbuf, tid, wave);
    else        fa_stage(kb, vtb, 1024, 64, smem, nbuf, 32768 + nbuf, tid, wave);
    fa_compute<128>(smem, buf, 32768 + buf, qa, lPw, quad, l16, accO, mrow, lrow);
    __syncthreads();
  }
  fa_compute<64>(smem, 0, 32768, qa, lPw, quad, l16, accO, mrow, lrow);

  f32x4 inv;
  inv[0] = 1.f / lrow[0]; inv[1] = 1.f / lrow[1];
  inv[2] = 1.f / lrow[2]; inv[3] = 1.f / lrow[3];
#pragma unroll
  for (int nd = 0; nd < 4; ++nd) {
    f32x4 o = accO[nd] * inv;
#pragma unroll
    for (int r = 0; r < 4; ++r)
      att[(long long)(qrow0 + quad * 4 + r) * 1024 +
          h * 64 + nd * 16 + l16] = f2b(o[r]);
  }
}

// ---------------------------------------------------------------------------
// Elementwise / helper kernels
// ---------------------------------------------------------------------------
__global__ void init_x_kernel(const void* __restrict__ x, const int* __restrict__ flag,
                              float* __restrict__ xf, bf16* __restrict__ xbf) {
  int i = blockIdx.x * 256 + threadIdx.x;
  float v = (*flag) ? b2f(((const bf16*)x)[i]) : ((const float*)x)[i];
  xf[i] = v;
  xbf[i] = f2b(v);
}

__global__ void transpose_w(const void* __restrict__ in, bf16* __restrict__ out,
                            int R, int C, const int* __restrict__ flag) {
  __shared__ bf16 tile[32][33];
  long long zoff = (long long)blockIdx.z * R * C;
  const bf16* inb = (const bf16*)in + zoff;
  const float* inf = (const float*)in + zoff;
  out += zoff;
  int tx = threadIdx.x, ty = threadIdx.y;
  int c0 = blockIdx.x * 32, r0 = blockIdx.y * 32;
  int isb = *flag;
#pragma unroll
  for (int i = 0; i < 4; ++i) {
    long long off = (long long)(r0 + ty + i * 8) * C + (c0 + tx);
    tile[ty + i * 8][tx] = isb ? inb[off] : f2b(inf[off]);
  }
  __syncthreads();
#pragma unroll
  for (int i = 0; i < 4; ++i)
    out[(long long)(c0 + ty + i * 8) * R + (r0 + tx)] = tile[tx][ty + i * 8];
}

__global__ void rotary_q_kernel(bf16* __restrict__ q, const bf16* __restrict__ srcf) {
  int idx = blockIdx.x * 256 + threadIdx.x;
  int row = idx >> 9;
  int p = idx & 511;
  int h = p >> 5, i = p & 31;
  int d0 = h * 64 + 2 * i;
  int ntok = row & 255;
  float f = b2f(srcf[ntok * 64 + 2 * i]);
  float c = cosf(f), s = sinf(f);
  long long base = (long long)row * 1024 + d0;
  float q0 = b2f(q[base]), q1 = b2f(q[base + 1]);
  q[base]     = f2b(q0 * c - q1 * s);
  q[base + 1] = f2b(q1 * c + q0 * s);
}

__global__ void k_bias_rot_kernel(bf16* __restrict__ k, const bf16* __restrict__ tgtf,
                                  const bf16* __restrict__ rpe,
                                  const int* __restrict__ ridx, int layer) {
  int idx = blockIdx.x * 256 + threadIdx.x;
  int b = idx >> 19;
  int rem = idx & ((1 << 19) - 1);
  int j = rem >> 9;
  int p = rem & 511;
  int h = p >> 5, i = p & 31;
  int d0 = h * 64 + 2 * i;
  float bias = b2f(rpe[(layer * 405 + ridx[j >> 8]) * 16 + h]);
  float f = b2f(tgtf[j * 64 + 2 * i]);
  float c = cosf(f), s = sinf(f);
  long long base = (long long)(b * 1088 + j) * 1024 + d0;
  float k0 = b2f(k[base]) + bias, k1 = b2f(k[base + 1]) + bias;
  k[base]     = f2b(k0 * c - k1 * s);
  k[base + 1] = f2b(k1 * c + k0 * s);
}

// ---------------------------------------------------------------------------
extern "C" void kernel_launch(void* const* d_in, const int* in_sizes, int n_in,
                              void* d_out, int out_size, void* d_ws, size_t ws_size,
                              hipStream_t stream) {
  (void)in_sizes; (void)n_in; (void)out_size; (void)ws_size;
  const void* x    = d_in[0];
  const void* cond = d_in[1];
  const void* Wq   = d_in[2];
  const void* Wk   = d_in[3];
  const void* Wv   = d_in[4];
  const void* Wo   = d_in[5];
  const void* bo   = d_in[6];
  const void* rpe  = d_in[7];
  const void* W1   = d_in[8];
  const void* b1   = d_in[9];
  const void* W2   = d_in[10];
  const void* b2   = d_in[11];
  const void* srcf = d_in[12];
  const void* tgtf = d_in[13];
  const int*  ridx = (const int*)d_in[14];

  char* w = (char*)d_ws;
  int* flag = (int*)w;   w += 256;
  bf16* WqT = (bf16*)w;  w += (size_t)2 * 1024 * 1024 * 2;
  bf16* WkT = (bf16*)w;  w += (size_t)2 * 1024 * 1024 * 2;
  bf16* WvT = (bf16*)w;  w += (size_t)2 * 1024 * 1024 * 2;
  bf16* WoT = (bf16*)w;  w += (size_t)2 * 1024 * 1024 * 2;
  bf16* W1T = (bf16*)w;  w += (size_t)2 * 8192 * 1024 * 2;
  bf16* W2T = (bf16*)w;  w += (size_t)2 * 4096 * 1024 * 2;
  bf16* condb = (bf16*)w; w += (size_t)8704 * 1024 * 2;
  bf16* bo_b = (bf16*)w;  w += 2048 * 2;
  bf16* rpe_b = (bf16*)w; w += 12960 * 2;
  bf16* b1_b = (bf16*)w;  w += 16384 * 2;
  bf16* b2_b = (bf16*)w;  w += 2048 * 2;
  bf16* srcf_b = (bf16*)w; w += 16384 * 2;
  bf16* tgtf_b = (bf16*)w; w += 65536 * 2;
  float* xf = (float*)w; w += (size_t)2048 * 1024 * 4;
  bf16* xbf = (bf16*)w;  w += (size_t)2048 * 1024 * 2;
  bf16* qbuf = (bf16*)w; w += (size_t)2048 * 1024 * 2;
  bf16* kbuf = (bf16*)w; w += (size_t)8704 * 1024 * 2;
  bf16* vTf = (bf16*)w;  w += (size_t)1024 * 8704 * 2;
  bf16* att = (bf16*)w;  w += (size_t)2048 * 1024 * 2;
  bf16* hgl = (bf16*)w;  w += (size_t)2048 * 8192 * 2;   // 32 MiB (pbuf alias)
  bf16* ybuf = (bf16*)w; w += (size_t)2048 * 4096 * 2;   // 16 MiB
  float* pbuf = (float*)hgl;  // split-K partials (4 x 8 MiB)

  detect_dtype<<<1, 1, 0, stream>>>((const unsigned int*)x, flag);

  convert_in<<<34816, 256, 0, stream>>>(cond, condb, 8704 * 1024, flag);
  convert_in<<<8, 256, 0, stream>>>(bo, bo_b, 2048, flag);
  convert_in<<<51, 256, 0, stream>>>(rpe, rpe_b, 12960, flag);
  convert_in<<<64, 256, 0, stream>>>(b1, b1_b, 16384, flag);
  convert_in<<<8, 256, 0, stream>>>(b2, b2_b, 2048, flag);
  convert_in<<<64, 256, 0, stream>>>(srcf, srcf_b, 16384, flag);
  convert_in<<<256, 256, 0, stream>>>(tgtf, tgtf_b, 65536, flag);

  dim3 tb(32, 8);
  transpose_w<<<dim3(32, 32, 2),  tb, 0, stream>>>(Wq, WqT, 1024, 1024, flag);
  transpose_w<<<dim3(32, 32, 2),  tb, 0, stream>>>(Wk, WkT, 1024, 1024, flag);
  transpose_w<<<dim3(32, 32, 2),  tb, 0, stream>>>(Wv, WvT, 1024, 1024, flag);
  transpose_w<<<dim3(32, 32, 2),  tb, 0, stream>>>(Wo, WoT, 1024, 1024, flag);
  transpose_w<<<dim3(256, 32, 2), tb, 0, stream>>>(W1, W1T, 1024, 8192, flag);
  transpose_w<<<dim3(32, 128, 2), tb, 0, stream>>>(W2, W2T, 4096, 1024, flag);
  init_x_kernel<<<8192, 256, 0, stream>>>(x, flag, xf, xbf);

  for (int l = 0; l < 2; ++l) {
    const bf16* WqTl = WqT + (size_t)l * 1024 * 1024;
    const bf16* WkTl = WkT + (size_t)l * 1024 * 1024;
    const bf16* WvTl = WvT + (size_t)l * 1024 * 1024;
    const bf16* WoTl = WoT + (size_t)l * 1024 * 1024;
    const bf16* W1Tl = W1T + (size_t)l * 8192 * 1024;
    const bf16* W2Tl = W2T + (size_t)l * 4096 * 1024;

    // TAG 0: q = x @ Wq   (M=2048, N=1024)
    gemm_bt<0><<<dim3(8, 16), 256, 0, stream>>>(xbf, 1024, WqTl, 1024, 1.f,
        nullptr, nullptr, nullptr, qbuf, 1024, 1024);
    rotary_q_kernel<<<4096, 256, 0, stream>>>(qbuf, srcf_b);
    // TAG 1: V^T = Wv^T @ cond^T   (M=1024, N=8704)
    gemm_bt<1><<<dim3(68, 8), 256, 0, stream>>>(WvTl, 1024, condb, 1024, 1.f,
        nullptr, nullptr, nullptr, vTf, 8704, 1024);
    // TAG 2: k = cond @ Wk   (M=8704, N=1024)
    gemm_bt<2><<<dim3(8, 68), 256, 0, stream>>>(condb, 1024, WkTl, 1024, 1.f,
        nullptr, nullptr, nullptr, kbuf, 1024, 1024);
    k_bias_rot_kernel<<<16384, 256, 0, stream>>>(kbuf, tgtf_b, rpe_b, ridx, l);
    // fused attention
    flash_attn<<<256, 512, 0, stream>>>(qbuf, kbuf, vTf, att);
    // TAG 3: x = x + O @ Wo + bo   (M=2048, N=1024)
    gemm_bt<3><<<dim3(8, 16), 256, 0, stream>>>(att, 1024, WoTl, 1024, 1.f,
        xf, bo_b + (size_t)l * 1024, xf, xbf, 1024, 1024);
    // FF1+GEGLU fused: y = a*gelu(g), tile covers a-col + matching g-col
    gemm256_geglu<<<dim3(32, 8), 512, 0, stream>>>(xbf, 1024, W1Tl, 1024,
        b1_b + (size_t)l * 8192, ybuf, 4096, 1024);
    // FF2 split-K into partials (alias hgl) + fused reduce
    gemm_splitk<<<dim3(8, 16, 4), 256, 0, stream>>>(ybuf, 4096, W2Tl, 4096,
                                                    pbuf, 1024, 2048, 1024);
    reduce_ff2<<<8192, 256, 0, stream>>>(pbuf, b2_b + (size_t)l * 1024, xf, xbf);
  }

  emit_kernel<<<8192, 256, 0, stream>>>(xf, flag, d_out);
}